// Round 12
// baseline (535.610 us; speedup 1.0000x reference)
//
#include <hip/hip_runtime.h>
#include <hip/hip_fp16.h>

#define N_NODES 100000
#define N_EDGES 400000
#define N_GRAPHS 5000
#define NPG 20
#define SCAN_NB 256
#define SCAN_CHUNK ((N_NODES + SCAN_NB - 1) / SCAN_NB)  // 391
#define TAB_STRIDE (256 * 128 + 128)  // T12[256][128] + v[128]
#define F1 16384  // ushorts per K=64 frag array (1024 frags * 16: hi8|lo8)
#define F2 32768  // ushorts per K=128 frag array (2048 frags * 16)
#define NB_ENC ((N_NODES + 255) / 256)   // 391
#define NB_HIST ((N_EDGES + 255) / 256)  // 1563

typedef __attribute__((ext_vector_type(8))) short bf16x8;
typedef __attribute__((ext_vector_type(4))) float f32x4;

__device__ __forceinline__ unsigned short f2bf(float f) {
  unsigned u = __float_as_uint(f);
  unsigned r = (u + 0x7FFFu + ((u >> 16) & 1u)) >> 16;
  return (unsigned short)r;
}
__device__ __forceinline__ float bf2f(unsigned short h) {
  return __uint_as_float(((unsigned)h) << 16);
}
__device__ __forceinline__ float4 h4_to_f4(const __half* p) {
  const __half2* q = (const __half2*)p;
  float2 a = __half22float2(q[0]);
  float2 b = __half22float2(q[1]);
  return make_float4(a.x, a.y, b.x, b.y);
}

// ---------------- fused prologue: encode_nodes | hist | tabs | prep ---------
__global__ __launch_bounds__(256) void k_prologue(
    const float* __restrict__ x, const float* __restrict__ atom_emb,
    const float* __restrict__ bool_emb, const float* __restrict__ Wn,
    const float* __restrict__ bn, float* __restrict__ h0,
    const int* __restrict__ dst, int* __restrict__ cnt,
    const float* __restrict__ Wedge1, const float* __restrict__ Wedge2,
    const float* __restrict__ bond_emb, const float* __restrict__ We,
    const float* __restrict__ be, float* __restrict__ tabs,
    const float* __restrict__ Wl1, const float* __restrict__ Wr1,
    const float* __restrict__ Wl2, const float* __restrict__ Wr2,
    unsigned short* __restrict__ fr) {
  int b = blockIdx.x, tid = threadIdx.x;
  if (b < NB_ENC) {
    // ---- node encoder: h0[N,64] (cols 52..63 zero) ----
    int n = b * 256 + tid;
    if (n >= N_NODES) return;
    const float* xr = x + (size_t)n * 14;
    float* h = h0 + (size_t)n * 64;
    int ai = (int)xr[0];
    #pragma unroll
    for (int j = 0; j < 16; j++) h[j] = atom_emb[ai * 16 + j];
    float xc[10];
    #pragma unroll
    for (int k = 0; k < 10; k++) xc[k] = xr[1 + k];
    #pragma unroll
    for (int c = 0; c < 30; c++) {
      float s = bn[c];
      #pragma unroll
      for (int k = 0; k < 10; k++) s += xc[k] * Wn[k * 30 + c];
      h[16 + c] = s;
    }
    #pragma unroll
    for (int t = 0; t < 3; t++) {
      int bb = (int)xr[11 + t];
      h[46 + 2 * t]     = bool_emb[2 * bb];
      h[46 + 2 * t + 1] = bool_emb[2 * bb + 1];
    }
    #pragma unroll
    for (int j = 52; j < 64; j++) h[j] = 0.0f;
  } else if (b < NB_ENC + NB_HIST) {
    // ---- in-degree histogram ----
    int e = (b - NB_ENC) * 256 + tid;
    if (e >= N_EDGES) return;
    atomicAdd(cnt + dst[e], 1);
  } else if (b == NB_ENC + NB_HIST) {
    // ---- fused logit table: T12[combo*32+bi], v ----
    int s = tid >> 7, c = tid & 127;
    const float* W = s ? Wedge2 : Wedge1;
    float* T12 = tabs + s * TAB_STRIDE;
    float* v   = T12 + 256 * 128;
    float w8 = W[8 * 128 + c], w9 = W[9 * 128 + c];
    v[c] = We[0] * w8 + We[1] * w9;
    float cst = be[0] * w8 + be[1] * w9;
    float bond[22];
    for (int bb = 0; bb < 22; bb++) {
      float acc = 0.f;
      #pragma unroll
      for (int k = 0; k < 8; k++) acc += bond_emb[bb * 8 + k] * W[k * 128 + c];
      bond[bb] = acc;
    }
    for (int combo = 0; combo < 8; combo++) {
      float t2 = cst;
      #pragma unroll
      for (int tt = 0; tt < 3; tt++) {
        int bt = (combo >> tt) & 1;
        t2 += bool_emb[bt * 2 + 0] * W[(10 + 2 * tt + 0) * 128 + c];
        t2 += bool_emb[bt * 2 + 1] * W[(10 + 2 * tt + 1) * 128 + c];
      }
      for (int bb = 0; bb < 22; bb++)
        T12[(combo * 32 + bb) * 128 + c] = bond[bb] + t2;
    }
  } else {
    // ---- W -> MFMA B-fragment prep (interleaved hi8|lo8) ----
    int g = (b - (NB_ENC + NB_HIST + 1)) * 256 + tid;
    const float* W; int K; unsigned short* base; int fl;
    if (g < 1024)      { W = Wl1; K = 52;  base = fr;               fl = g; }
    else if (g < 2048) { W = Wr1; K = 52;  base = fr + F1;          fl = g - 1024; }
    else if (g < 4096) { W = Wl2; K = 128; base = fr + 2 * F1;      fl = g - 2048; }
    else if (g < 6144) { W = Wr2; K = 128; base = fr + 2 * F1 + F2; fl = g - 4096; }
    else return;
    int l = fl & 63, ctn = fl >> 6;
    int tn = ctn & 7, c = ctn >> 3;
    int n = tn * 16 + (l & 15);
    int kb = c * 32 + (l >> 4) * 8;
    unsigned h8[8], l8[8];
    #pragma unroll
    for (int j = 0; j < 8; j++) {
      int k = kb + j;
      float v = (k < K) ? W[(size_t)k * 128 + n] : 0.f;
      unsigned short hh = f2bf(v);
      h8[j] = hh;
      l8[j] = f2bf(v - bf2f(hh));
    }
    uint4 hv = make_uint4(h8[0] | (h8[1] << 16), h8[2] | (h8[3] << 16),
                          h8[4] | (h8[5] << 16), h8[6] | (h8[7] << 16));
    uint4 lv = make_uint4(l8[0] | (l8[1] << 16), l8[2] | (l8[3] << 16),
                          l8[4] | (l8[5] << 16), l8[6] | (l8[7] << 16));
    *(uint4*)(base + (size_t)fl * 16) = hv;
    *(uint4*)(base + (size_t)fl * 16 + 8) = lv;
  }
}

// ---------------- hierarchical scan over (cnt[n]+1), 3 phases ---------------
__global__ __launch_bounds__(256) void k_scan1(const int* __restrict__ cnt,
                                               int* __restrict__ bsum) {
  __shared__ int red[256];
  int b = blockIdx.x, t = threadIdx.x;
  int beg = b * SCAN_CHUNK;
  int end = beg + SCAN_CHUNK; if (end > N_NODES) end = N_NODES;
  int s = 0;
  for (int i = beg + t; i < end; i += 256) s += cnt[i] + 1;
  red[t] = s;
  __syncthreads();
  for (int off = 128; off > 0; off >>= 1) {
    if (t < off) red[t] += red[t + off];
    __syncthreads();
  }
  if (t == 0) bsum[b] = red[0];
}

__global__ __launch_bounds__(256) void k_scan2(int* __restrict__ bsum) {
  __shared__ int sh[256];
  int t = threadIdx.x;
  sh[t] = bsum[t];
  __syncthreads();
  for (int off = 1; off < 256; off <<= 1) {
    int v = (t >= off) ? sh[t - off] : 0;
    __syncthreads();
    sh[t] += v;
    __syncthreads();
  }
  bsum[t] = (t > 0) ? sh[t - 1] : 0;  // exclusive
}

__global__ __launch_bounds__(256) void k_scan3(const int* __restrict__ cnt,
                                               const int* __restrict__ bsum,
                                               int* __restrict__ indptr,
                                               int* __restrict__ cursor) {
  __shared__ int sh[256];
  __shared__ int carry;
  int b = blockIdx.x, t = threadIdx.x;
  int beg = b * SCAN_CHUNK;
  int end = beg + SCAN_CHUNK; if (end > N_NODES) end = N_NODES;
  if (t == 0) carry = bsum[b];
  __syncthreads();
  for (int base = beg; base < end; base += 256) {
    int i = base + t;
    int v = (i < end) ? cnt[i] + 1 : 0;
    sh[t] = v;
    __syncthreads();
    for (int off = 1; off < 256; off <<= 1) {
      int u = (t >= off) ? sh[t - off] : 0;
      __syncthreads();
      sh[t] += u;
      __syncthreads();
    }
    int excl = sh[t] - v;
    if (i < end) {
      int val = carry + excl;
      indptr[i] = val;
      cursor[i] = val;
    }
    __syncthreads();
    if (t == 255) carry += sh[255];
    __syncthreads();
  }
  if (b == 0 && t == 0) indptr[N_NODES] = N_EDGES + N_NODES;
}

// ---------------- CSR fill: ordinary edges into slots [beg, end-1) ----------
__global__ void k_fill(const int* __restrict__ srcA,
                       const int* __restrict__ dst,
                       const float* __restrict__ eattr,
                       int* __restrict__ cursor,
                       int4* __restrict__ scode) {
  int e = blockIdx.x * blockDim.x + threadIdx.x;
  if (e >= N_EDGES) return;
  const float* r = eattr + (size_t)e * 5;
  int bi = (int)r[0];
  float ec = r[1];
  int combo = (int)r[2] + 2 * (int)r[3] + 4 * (int)r[4];
  int meta = bi | (combo << 5);
  int d = dst[e];
  int p = atomicAdd(&cursor[d], 1);
  scode[p] = make_int4(srcA[e], meta, __float_as_int(ec), 0);
}

// ---------------- MFMA dual GEMM, M=16/wave, LDS-staged B -------------------
// 4 waves/block share each 32 KB chunk stage (L/R x hi/lo de-interleaved to
// 4 x 8 KB regions -> ds_read_b128 is the standard contiguous-16B pattern).
template <int KPAD>
__global__ __launch_bounds__(256, 3) void k_gemm2m(const float* __restrict__ A,
                                                   const unsigned short* __restrict__ WfL,
                                                   const unsigned short* __restrict__ WfR,
                                                   const float* __restrict__ bl_,
                                                   const float* __restrict__ br_,
                                                   __half* __restrict__ outl,
                                                   __half* __restrict__ outr) {
  __shared__ unsigned short Bs[4][4096];  // L_hi, L_lo, R_hi, R_lo (8 KB each)
  const int tid = threadIdx.x;
  const int wv = tid >> 6, lane = tid & 63;
  const int tw = blockIdx.x * 4 + wv;
  const bool active = (tw < N_NODES / 16);  // tail waves stay for barriers
  const int ml = lane & 15, q = lane >> 4;
  const int m0 = active ? tw * 16 : 0;
  f32x4 accL[8], accR[8];
  #pragma unroll
  for (int t = 0; t < 8; t++) {
    accL[t] = (f32x4){0.f, 0.f, 0.f, 0.f};
    accR[t] = (f32x4){0.f, 0.f, 0.f, 0.f};
  }
  const float* ar0 = A + (size_t)(m0 + ml) * KPAD + q * 8;
  constexpr int NC = KPAD / 32;
  for (int c = 0; c < NC; c++) {
    // stage chunk: 512 frags per W, de-interleave hi/lo
    #pragma unroll
    for (int i0 = 0; i0 < 512; i0 += 256) {
      int i = i0 + tid;
      size_t g = ((size_t)c * 512 + i) * 16;
      uint4 hL = *(const uint4*)(WfL + g);
      uint4 lL = *(const uint4*)(WfL + g + 8);
      uint4 hR = *(const uint4*)(WfR + g);
      uint4 lR = *(const uint4*)(WfR + g + 8);
      *(uint4*)(&Bs[0][i * 8]) = hL;
      *(uint4*)(&Bs[1][i * 8]) = lL;
      *(uint4*)(&Bs[2][i * 8]) = hR;
      *(uint4*)(&Bs[3][i * 8]) = lR;
    }
    __syncthreads();
    float4 x0 = *(const float4*)(ar0 + c * 32);
    float4 x1 = *(const float4*)(ar0 + c * 32 + 4);
    float av[8] = {x0.x, x0.y, x0.z, x0.w, x1.x, x1.y, x1.z, x1.w};
    bf16x8 ah, al;
    #pragma unroll
    for (int j = 0; j < 8; j++) {
      unsigned short hh = f2bf(av[j]);
      ah[j] = (short)hh;
      al[j] = (short)f2bf(av[j] - bf2f(hh));
    }
    #pragma unroll
    for (int t = 0; t < 8; t++) {
      int idx = (t * 64 + lane) * 8;
      bf16x8 bhL = *(const bf16x8*)(&Bs[0][idx]);
      bf16x8 blL = *(const bf16x8*)(&Bs[1][idx]);
      bf16x8 bhR = *(const bf16x8*)(&Bs[2][idx]);
      bf16x8 blR = *(const bf16x8*)(&Bs[3][idx]);
      accL[t] = __builtin_amdgcn_mfma_f32_16x16x32_bf16(ah, bhL, accL[t], 0, 0, 0);
      accL[t] = __builtin_amdgcn_mfma_f32_16x16x32_bf16(al, bhL, accL[t], 0, 0, 0);
      accL[t] = __builtin_amdgcn_mfma_f32_16x16x32_bf16(ah, blL, accL[t], 0, 0, 0);
      accR[t] = __builtin_amdgcn_mfma_f32_16x16x32_bf16(ah, bhR, accR[t], 0, 0, 0);
      accR[t] = __builtin_amdgcn_mfma_f32_16x16x32_bf16(al, bhR, accR[t], 0, 0, 0);
      accR[t] = __builtin_amdgcn_mfma_f32_16x16x32_bf16(ah, blR, accR[t], 0, 0, 0);
    }
    __syncthreads();
  }
  if (!active) return;
  // epilogue: C/D layout col=lane&15, row=quad*4+reg
  #pragma unroll
  for (int t = 0; t < 8; t++) {
    int n = t * 16 + ml;
    float bL = bl_[n], bR = br_[n];
    #pragma unroll
    for (int r = 0; r < 4; r++) {
      int row = m0 + q * 4 + r;
      outl[(size_t)row * 128 + n] = __float2half(accL[t][r] + bL);
      outr[(size_t)row * 128 + n] = __float2half(accR[t][r] + bR);
    }
  }
}

// ---------------- GATv2 edge pass: 32 lanes/node, fp16 xl/xr ----------------
// LAST=true: fuse global_max_pool — outputs are post-ReLU (>=0) so fp32 max
// == int atomicMax on the bit pattern (d_out zero-initialized).
template <bool LAST>
__global__ __launch_bounds__(256) void k_gat(const __half* __restrict__ xl,
                                             const __half* __restrict__ xr,
                                             const int* __restrict__ indptr,
                                             const int4* __restrict__ scode,
                                             const float* __restrict__ tabs,
                                             const float* __restrict__ att,
                                             const float* __restrict__ bias,
                                             float* __restrict__ hout,
                                             int* __restrict__ gout) {
  int wid = (blockIdx.x * 256 + threadIdx.x) >> 6;
  int nw = (gridDim.x * 256) >> 6;
  int lane = threadIdx.x & 63;
  int half = lane >> 5;
  int c = (lane & 31) * 4;  // 4 channels per lane
  const float* T12 = tabs;  // 256 x 128
  float4 v4 = *(const float4*)(tabs + 256 * 128 + c);
  float4 a4 = *(const float4*)(att + c);
  float4 b4 = *(const float4*)(bias + c);
  wid = __builtin_amdgcn_readfirstlane(wid);
  for (int nb = wid * 2; nb < N_NODES; nb += nw * 2) {
    int n = nb + half;
    int beg = indptr[n], end1 = indptr[n + 1] - 1;  // end1 = self-loop slot
    int last = (end1 > beg) ? end1 - 1 : beg;       // clamp (may be unwritten!)
    float4 xrv = h4_to_f4(xr + (size_t)n * 128 + c);
    float denom = 0.f;
    float4 acc = make_float4(0.f, 0.f, 0.f, 0.f);
    float4 els = make_float4(0.f, 0.f, 0.f, 0.f);
    int my_it = (end1 - beg + 3) >> 2;
    int ot = __shfl_xor(my_it, 32, 64);
    int iters = my_it > ot ? my_it : ot;  // wave-uniform
    for (int it = 0; it < iters; it++) {
      int j = beg + it * 4;
      int4 sc4[4]; float4 xlv[4]; float tt[4]; float4 el[4];
      bool val[4];
      #pragma unroll
      for (int u = 0; u < 4; u++) {
        val[u] = (j + u < end1);  // uniform within half
        int jj = val[u] ? j + u : last;
        sc4[u] = scode[jj];
      }
      #pragma unroll
      for (int u = 0; u < 4; u++) {
        int s = val[u] ? sc4[u].x : n;  // NEVER use poison as an address
        xlv[u] = h4_to_f4(xl + (size_t)s * 128 + c);
      }
      #pragma unroll
      for (int u = 0; u < 4; u++) {
        int meta = val[u] ? (sc4[u].y & 255) : 0;
        float ec = val[u] ? __int_as_float(sc4[u].z) : 0.f;
        float4 t12 = *(const float4*)(T12 + (size_t)meta * 128 + c);
        el[u].x = t12.x + ec * v4.x;
        el[u].y = t12.y + ec * v4.y;
        el[u].z = t12.z + ec * v4.z;
        el[u].w = t12.w + ec * v4.w;
        float m0 = xlv[u].x + xrv.x + el[u].x;
        float m1 = xlv[u].y + xrv.y + el[u].y;
        float m2 = xlv[u].z + xrv.z + el[u].z;
        float m3 = xlv[u].w + xrv.w + el[u].w;
        float l0 = m0 > 0.f ? m0 : 0.2f * m0;
        float l1 = m1 > 0.f ? m1 : 0.2f * m1;
        float l2 = m2 > 0.f ? m2 : 0.2f * m2;
        float l3 = m3 > 0.f ? m3 : 0.2f * m3;
        tt[u] = l0 * a4.x + l1 * a4.y + l2 * a4.z + l3 * a4.w;
      }
      // 8 independent half-wave reduction chains (4 per node), 5 steps
      #pragma unroll
      for (int off = 1; off < 32; off <<= 1) {
        tt[0] += __shfl_xor(tt[0], off, 64);
        tt[1] += __shfl_xor(tt[1], off, 64);
        tt[2] += __shfl_xor(tt[2], off, 64);
        tt[3] += __shfl_xor(tt[3], off, 64);
      }
      #pragma unroll
      for (int u = 0; u < 4; u++) {
        float ex = val[u] ? __expf(tt[u]) : 0.f;
        denom += ex;
        acc.x += ex * xlv[u].x;
        acc.y += ex * xlv[u].y;
        acc.z += ex * xlv[u].z;
        acc.w += ex * xlv[u].w;
        els.x += val[u] ? el[u].x : 0.f;
        els.y += val[u] ? el[u].y : 0.f;
        els.z += val[u] ? el[u].z : 0.f;
        els.w += val[u] ? el[u].w : 0.f;
      }
    }
    // self-loop (always present, processed last)
    int cntn = end1 - beg;
    float inv_cnt = 1.0f / (float)(cntn > 0 ? cntn : 1);
    float4 xln = h4_to_f4(xl + (size_t)n * 128 + c);
    float m0 = xln.x + xrv.x + els.x * inv_cnt;
    float m1 = xln.y + xrv.y + els.y * inv_cnt;
    float m2 = xln.z + xrv.z + els.z * inv_cnt;
    float m3 = xln.w + xrv.w + els.w * inv_cnt;
    float l0 = m0 > 0.f ? m0 : 0.2f * m0;
    float l1 = m1 > 0.f ? m1 : 0.2f * m1;
    float l2 = m2 > 0.f ? m2 : 0.2f * m2;
    float l3 = m3 > 0.f ? m3 : 0.2f * m3;
    float ts = l0 * a4.x + l1 * a4.y + l2 * a4.z + l3 * a4.w;
    #pragma unroll
    for (int off = 1; off < 32; off <<= 1) ts += __shfl_xor(ts, off, 64);
    float ex = __expf(ts);
    denom += ex;
    acc.x += ex * xln.x;
    acc.y += ex * xln.y;
    acc.z += ex * xln.z;
    acc.w += ex * xln.w;
    float invd = 1.0f / denom;
    float o0 = acc.x * invd + b4.x;
    float o1 = acc.y * invd + b4.y;
    float o2 = acc.z * invd + b4.z;
    float o3 = acc.w * invd + b4.w;
    o0 = o0 > 0.f ? o0 : 0.f;
    o1 = o1 > 0.f ? o1 : 0.f;
    o2 = o2 > 0.f ? o2 : 0.f;
    o3 = o3 > 0.f ? o3 : 0.f;
    if (LAST) {
      int* op = gout + (size_t)(n / NPG) * 128 + c;
      atomicMax(op + 0, __float_as_int(o0));
      atomicMax(op + 1, __float_as_int(o1));
      atomicMax(op + 2, __float_as_int(o2));
      atomicMax(op + 3, __float_as_int(o3));
    } else {
      *(float4*)(hout + (size_t)n * 128 + c) = make_float4(o0, o1, o2, o3);
    }
  }
}

extern "C" void kernel_launch(void* const* d_in, const int* in_sizes, int n_in,
                              void* d_out, int out_size, void* d_ws, size_t ws_size,
                              hipStream_t stream) {
  (void)in_sizes; (void)n_in; (void)ws_size;
  const float* x        = (const float*)d_in[0];
  const int*   eindex   = (const int*)d_in[1];
  const float* eattr    = (const float*)d_in[2];
  const float* atom_emb = (const float*)d_in[4];
  const float* bond_emb = (const float*)d_in[5];
  const float* bool_emb = (const float*)d_in[6];
  const float* Wn   = (const float*)d_in[7];
  const float* bn   = (const float*)d_in[8];
  const float* We   = (const float*)d_in[9];
  const float* be   = (const float*)d_in[10];
  const float* Wl1  = (const float*)d_in[11];
  const float* bl1  = (const float*)d_in[12];
  const float* Wr1  = (const float*)d_in[13];
  const float* br1  = (const float*)d_in[14];
  const float* Wedge1 = (const float*)d_in[15];
  const float* att1 = (const float*)d_in[16];
  const float* bias1 = (const float*)d_in[17];
  const float* Wl2  = (const float*)d_in[18];
  const float* bl2  = (const float*)d_in[19];
  const float* Wr2  = (const float*)d_in[20];
  const float* br2  = (const float*)d_in[21];
  const float* Wedge2 = (const float*)d_in[22];
  const float* att2 = (const float*)d_in[23];
  const float* bias2 = (const float*)d_in[24];

  const int* srcA = eindex;
  const int* dstA = eindex + N_EDGES;

  char* p = (char*)d_ws;
  auto alloc = [&](size_t bytes) {
    char* r = p;
    p += (bytes + 255) & ~(size_t)255;
    return r;
  };
  float*  h0     = (float*)alloc((size_t)N_NODES * 64 * 4);
  float*  h      = (float*)alloc((size_t)N_NODES * 128 * 4);
  __half* xl     = (__half*)alloc((size_t)N_NODES * 128 * 2);
  __half* xrb    = (__half*)alloc((size_t)N_NODES * 128 * 2);
  int*    cnt    = (int*)alloc((size_t)N_NODES * 4);
  int*    indptr = (int*)alloc((size_t)(N_NODES + 1) * 4);
  int*    cursor = (int*)alloc((size_t)N_NODES * 4);
  int4*   scode  = (int4*)alloc((size_t)(N_EDGES + N_NODES) * 16);
  float*  tabs   = (float*)alloc((size_t)2 * TAB_STRIDE * 4);
  unsigned short* wfrag = (unsigned short*)alloc((size_t)(2 * F1 + 2 * F2) * 2);
  int*    bsum   = (int*)alloc((size_t)SCAN_NB * 4);

  hipMemsetAsync(cnt, 0, (size_t)N_NODES * 4, stream);
  hipMemsetAsync(d_out, 0, (size_t)out_size * 4, stream);  // 0.0f = max identity (post-ReLU)

  // fused prologue: encode | hist | tabs | prep
  k_prologue<<<NB_ENC + NB_HIST + 1 + 24, 256, 0, stream>>>(
      x, atom_emb, bool_emb, Wn, bn, h0, dstA, cnt,
      Wedge1, Wedge2, bond_emb, We, be, tabs,
      Wl1, Wr1, Wl2, Wr2, wfrag);
  k_scan1<<<SCAN_NB, 256, 0, stream>>>(cnt, bsum);
  k_scan2<<<1, 256, 0, stream>>>(bsum);
  k_scan3<<<SCAN_NB, 256, 0, stream>>>(cnt, bsum, indptr, cursor);
  k_fill<<<(N_EDGES + 255) / 256, 256, 0, stream>>>(srcA, dstA, eattr, cursor, scode);

  const unsigned short* f_l1 = wfrag;
  const unsigned short* f_r1 = wfrag + F1;
  const unsigned short* f_l2 = wfrag + 2 * F1;
  const unsigned short* f_r2 = wfrag + 2 * F1 + F2;

  const int GB2 = (N_NODES / 16 + 3) / 4;  // 1563 blocks of 4 waves

  // layer 1 (K=52 zero-padded to 64)
  k_gemm2m<64><<<GB2, 256, 0, stream>>>(h0, f_l1, f_r1, bl1, br1, xl, xrb);
  k_gat<false><<<2048, 256, 0, stream>>>(xl, xrb, indptr, scode, tabs, att1, bias1, h, nullptr);

  // layer 2 (K=128)
  k_gemm2m<128><<<GB2, 256, 0, stream>>>(h, f_l2, f_r2, bl2, br2, xl, xrb);
  k_gat<false><<<2048, 256, 0, stream>>>(xl, xrb, indptr, scode, tabs + TAB_STRIDE, att2, bias2, h, nullptr);

  // layer 3 (shared weights with layer 2) — fused global_max_pool readout
  k_gemm2m<128><<<GB2, 256, 0, stream>>>(h, f_l2, f_r2, bl2, br2, xl, xrb);
  k_gat<true><<<2048, 256, 0, stream>>>(xl, xrb, indptr, scode, tabs + TAB_STRIDE, att2, bias2, nullptr, (int*)d_out);
}

// Round 13
// 431.542 us; speedup vs baseline: 1.2412x; 1.2412x over previous
//
#include <hip/hip_runtime.h>
#include <hip/hip_fp16.h>

#define N_NODES 100000
#define N_EDGES 400000
#define N_GRAPHS 5000
#define NPG 20
#define SCAN_NB 256
#define SCAN_CHUNK ((N_NODES + SCAN_NB - 1) / SCAN_NB)  // 391
#define TAB_STRIDE (256 * 128 + 128)  // T12[256][128] + v[128]
#define F1 16384  // ushorts per K=64 frag array (1024 frags * 16: hi8|lo8)
#define F2 32768  // ushorts per K=128 frag array (2048 frags * 16)
#define NB_ENC ((N_NODES + 255) / 256)   // 391
#define NB_HIST ((N_EDGES + 255) / 256)  // 1563

typedef __attribute__((ext_vector_type(8))) short bf16x8;
typedef __attribute__((ext_vector_type(4))) float f32x4;

__device__ __forceinline__ unsigned short f2bf(float f) {
  unsigned u = __float_as_uint(f);
  unsigned r = (u + 0x7FFFu + ((u >> 16) & 1u)) >> 16;
  return (unsigned short)r;
}
__device__ __forceinline__ float bf2f(unsigned short h) {
  return __uint_as_float(((unsigned)h) << 16);
}
__device__ __forceinline__ float4 h4_to_f4(const __half* p) {
  const __half2* q = (const __half2*)p;
  float2 a = __half22float2(q[0]);
  float2 b = __half22float2(q[1]);
  return make_float4(a.x, a.y, b.x, b.y);
}

// ---------------- fused prologue: encode_nodes | hist | tabs | prep ---------
__global__ __launch_bounds__(256) void k_prologue(
    const float* __restrict__ x, const float* __restrict__ atom_emb,
    const float* __restrict__ bool_emb, const float* __restrict__ Wn,
    const float* __restrict__ bn, float* __restrict__ h0,
    const int* __restrict__ dst, int* __restrict__ cnt,
    const float* __restrict__ Wedge1, const float* __restrict__ Wedge2,
    const float* __restrict__ bond_emb, const float* __restrict__ We,
    const float* __restrict__ be, float* __restrict__ tabs,
    const float* __restrict__ Wl1, const float* __restrict__ Wr1,
    const float* __restrict__ Wl2, const float* __restrict__ Wr2,
    unsigned short* __restrict__ fr) {
  int b = blockIdx.x, tid = threadIdx.x;
  if (b < NB_ENC) {
    // ---- node encoder: h0[N,64] (cols 52..63 zero) ----
    int n = b * 256 + tid;
    if (n >= N_NODES) return;
    const float* xr = x + (size_t)n * 14;
    float* h = h0 + (size_t)n * 64;
    int ai = (int)xr[0];
    #pragma unroll
    for (int j = 0; j < 16; j++) h[j] = atom_emb[ai * 16 + j];
    float xc[10];
    #pragma unroll
    for (int k = 0; k < 10; k++) xc[k] = xr[1 + k];
    #pragma unroll
    for (int c = 0; c < 30; c++) {
      float s = bn[c];
      #pragma unroll
      for (int k = 0; k < 10; k++) s += xc[k] * Wn[k * 30 + c];
      h[16 + c] = s;
    }
    #pragma unroll
    for (int t = 0; t < 3; t++) {
      int bb = (int)xr[11 + t];
      h[46 + 2 * t]     = bool_emb[2 * bb];
      h[46 + 2 * t + 1] = bool_emb[2 * bb + 1];
    }
    #pragma unroll
    for (int j = 52; j < 64; j++) h[j] = 0.0f;
  } else if (b < NB_ENC + NB_HIST) {
    // ---- in-degree histogram ----
    int e = (b - NB_ENC) * 256 + tid;
    if (e >= N_EDGES) return;
    atomicAdd(cnt + dst[e], 1);
  } else if (b == NB_ENC + NB_HIST) {
    // ---- fused logit table: T12[combo*32+bi], v ----
    int s = tid >> 7, c = tid & 127;
    const float* W = s ? Wedge2 : Wedge1;
    float* T12 = tabs + s * TAB_STRIDE;
    float* v   = T12 + 256 * 128;
    float w8 = W[8 * 128 + c], w9 = W[9 * 128 + c];
    v[c] = We[0] * w8 + We[1] * w9;
    float cst = be[0] * w8 + be[1] * w9;
    float bond[22];
    for (int bb = 0; bb < 22; bb++) {
      float acc = 0.f;
      #pragma unroll
      for (int k = 0; k < 8; k++) acc += bond_emb[bb * 8 + k] * W[k * 128 + c];
      bond[bb] = acc;
    }
    for (int combo = 0; combo < 8; combo++) {
      float t2 = cst;
      #pragma unroll
      for (int tt = 0; tt < 3; tt++) {
        int bt = (combo >> tt) & 1;
        t2 += bool_emb[bt * 2 + 0] * W[(10 + 2 * tt + 0) * 128 + c];
        t2 += bool_emb[bt * 2 + 1] * W[(10 + 2 * tt + 1) * 128 + c];
      }
      for (int bb = 0; bb < 22; bb++)
        T12[(combo * 32 + bb) * 128 + c] = bond[bb] + t2;
    }
  } else {
    // ---- W -> MFMA B-fragment prep (interleaved hi8|lo8) ----
    int g = (b - (NB_ENC + NB_HIST + 1)) * 256 + tid;
    const float* W; int K; unsigned short* base; int fl;
    if (g < 1024)      { W = Wl1; K = 52;  base = fr;               fl = g; }
    else if (g < 2048) { W = Wr1; K = 52;  base = fr + F1;          fl = g - 1024; }
    else if (g < 4096) { W = Wl2; K = 128; base = fr + 2 * F1;      fl = g - 2048; }
    else if (g < 6144) { W = Wr2; K = 128; base = fr + 2 * F1 + F2; fl = g - 4096; }
    else return;
    int l = fl & 63, ctn = fl >> 6;
    int tn = ctn & 7, c = ctn >> 3;
    int n = tn * 16 + (l & 15);
    int kb = c * 32 + (l >> 4) * 8;
    unsigned h8[8], l8[8];
    #pragma unroll
    for (int j = 0; j < 8; j++) {
      int k = kb + j;
      float v = (k < K) ? W[(size_t)k * 128 + n] : 0.f;
      unsigned short hh = f2bf(v);
      h8[j] = hh;
      l8[j] = f2bf(v - bf2f(hh));
    }
    uint4 hv = make_uint4(h8[0] | (h8[1] << 16), h8[2] | (h8[3] << 16),
                          h8[4] | (h8[5] << 16), h8[6] | (h8[7] << 16));
    uint4 lv = make_uint4(l8[0] | (l8[1] << 16), l8[2] | (l8[3] << 16),
                          l8[4] | (l8[5] << 16), l8[6] | (l8[7] << 16));
    *(uint4*)(base + (size_t)fl * 16) = hv;
    *(uint4*)(base + (size_t)fl * 16 + 8) = lv;
  }
}

// ---------------- hierarchical scan over (cnt[n]+1), 3 phases ---------------
__global__ __launch_bounds__(256) void k_scan1(const int* __restrict__ cnt,
                                               int* __restrict__ bsum) {
  __shared__ int red[256];
  int b = blockIdx.x, t = threadIdx.x;
  int beg = b * SCAN_CHUNK;
  int end = beg + SCAN_CHUNK; if (end > N_NODES) end = N_NODES;
  int s = 0;
  for (int i = beg + t; i < end; i += 256) s += cnt[i] + 1;
  red[t] = s;
  __syncthreads();
  for (int off = 128; off > 0; off >>= 1) {
    if (t < off) red[t] += red[t + off];
    __syncthreads();
  }
  if (t == 0) bsum[b] = red[0];
}

__global__ __launch_bounds__(256) void k_scan2(int* __restrict__ bsum) {
  __shared__ int sh[256];
  int t = threadIdx.x;
  sh[t] = bsum[t];
  __syncthreads();
  for (int off = 1; off < 256; off <<= 1) {
    int v = (t >= off) ? sh[t - off] : 0;
    __syncthreads();
    sh[t] += v;
    __syncthreads();
  }
  bsum[t] = (t > 0) ? sh[t - 1] : 0;  // exclusive
}

__global__ __launch_bounds__(256) void k_scan3(const int* __restrict__ cnt,
                                               const int* __restrict__ bsum,
                                               int* __restrict__ indptr,
                                               int* __restrict__ cursor) {
  __shared__ int sh[256];
  __shared__ int carry;
  int b = blockIdx.x, t = threadIdx.x;
  int beg = b * SCAN_CHUNK;
  int end = beg + SCAN_CHUNK; if (end > N_NODES) end = N_NODES;
  if (t == 0) carry = bsum[b];
  __syncthreads();
  for (int base = beg; base < end; base += 256) {
    int i = base + t;
    int v = (i < end) ? cnt[i] + 1 : 0;
    sh[t] = v;
    __syncthreads();
    for (int off = 1; off < 256; off <<= 1) {
      int u = (t >= off) ? sh[t - off] : 0;
      __syncthreads();
      sh[t] += u;
      __syncthreads();
    }
    int excl = sh[t] - v;
    if (i < end) {
      int val = carry + excl;
      indptr[i] = val;
      cursor[i] = val;
    }
    __syncthreads();
    if (t == 255) carry += sh[255];
    __syncthreads();
  }
  if (b == 0 && t == 0) indptr[N_NODES] = N_EDGES + N_NODES;
}

// ---------------- CSR fill: ordinary edges into slots [beg, end-1) ----------
__global__ void k_fill(const int* __restrict__ srcA,
                       const int* __restrict__ dst,
                       const float* __restrict__ eattr,
                       int* __restrict__ cursor,
                       int4* __restrict__ scode) {
  int e = blockIdx.x * blockDim.x + threadIdx.x;
  if (e >= N_EDGES) return;
  const float* r = eattr + (size_t)e * 5;
  int bi = (int)r[0];
  float ec = r[1];
  int combo = (int)r[2] + 2 * (int)r[3] + 4 * (int)r[4];
  int meta = bi | (combo << 5);
  int d = dst[e];
  int p = atomicAdd(&cursor[d], 1);
  scode[p] = make_int4(srcA[e], meta, __float_as_int(ec), 0);
}

// ---------------- MFMA dual GEMM, M=16/wave, LDS-staged B -------------------
// 4 waves/block share each 32 KB chunk stage (L/R x hi/lo de-interleaved to
// 4 x 8 KB regions -> ds_read_b128 is the standard contiguous-16B pattern).
template <int KPAD>
__global__ __launch_bounds__(256, 3) void k_gemm2m(const float* __restrict__ A,
                                                   const unsigned short* __restrict__ WfL,
                                                   const unsigned short* __restrict__ WfR,
                                                   const float* __restrict__ bl_,
                                                   const float* __restrict__ br_,
                                                   __half* __restrict__ outl,
                                                   __half* __restrict__ outr) {
  __shared__ unsigned short Bs[4][4096];  // L_hi, L_lo, R_hi, R_lo (8 KB each)
  const int tid = threadIdx.x;
  const int wv = tid >> 6, lane = tid & 63;
  const int tw = blockIdx.x * 4 + wv;
  const bool active = (tw < N_NODES / 16);  // tail waves stay for barriers
  const int ml = lane & 15, q = lane >> 4;
  const int m0 = active ? tw * 16 : 0;
  f32x4 accL[8], accR[8];
  #pragma unroll
  for (int t = 0; t < 8; t++) {
    accL[t] = (f32x4){0.f, 0.f, 0.f, 0.f};
    accR[t] = (f32x4){0.f, 0.f, 0.f, 0.f};
  }
  const float* ar0 = A + (size_t)(m0 + ml) * KPAD + q * 8;
  constexpr int NC = KPAD / 32;
  for (int c = 0; c < NC; c++) {
    // stage chunk: 512 frags per W, de-interleave hi/lo
    #pragma unroll
    for (int i0 = 0; i0 < 512; i0 += 256) {
      int i = i0 + tid;
      size_t g = ((size_t)c * 512 + i) * 16;
      uint4 hL = *(const uint4*)(WfL + g);
      uint4 lL = *(const uint4*)(WfL + g + 8);
      uint4 hR = *(const uint4*)(WfR + g);
      uint4 lR = *(const uint4*)(WfR + g + 8);
      *(uint4*)(&Bs[0][i * 8]) = hL;
      *(uint4*)(&Bs[1][i * 8]) = lL;
      *(uint4*)(&Bs[2][i * 8]) = hR;
      *(uint4*)(&Bs[3][i * 8]) = lR;
    }
    __syncthreads();
    float4 x0 = *(const float4*)(ar0 + c * 32);
    float4 x1 = *(const float4*)(ar0 + c * 32 + 4);
    float av[8] = {x0.x, x0.y, x0.z, x0.w, x1.x, x1.y, x1.z, x1.w};
    bf16x8 ah, al;
    #pragma unroll
    for (int j = 0; j < 8; j++) {
      unsigned short hh = f2bf(av[j]);
      ah[j] = (short)hh;
      al[j] = (short)f2bf(av[j] - bf2f(hh));
    }
    #pragma unroll
    for (int t = 0; t < 8; t++) {
      int idx = (t * 64 + lane) * 8;
      bf16x8 bhL = *(const bf16x8*)(&Bs[0][idx]);
      bf16x8 blL = *(const bf16x8*)(&Bs[1][idx]);
      bf16x8 bhR = *(const bf16x8*)(&Bs[2][idx]);
      bf16x8 blR = *(const bf16x8*)(&Bs[3][idx]);
      accL[t] = __builtin_amdgcn_mfma_f32_16x16x32_bf16(ah, bhL, accL[t], 0, 0, 0);
      accL[t] = __builtin_amdgcn_mfma_f32_16x16x32_bf16(al, bhL, accL[t], 0, 0, 0);
      accL[t] = __builtin_amdgcn_mfma_f32_16x16x32_bf16(ah, blL, accL[t], 0, 0, 0);
      accR[t] = __builtin_amdgcn_mfma_f32_16x16x32_bf16(ah, bhR, accR[t], 0, 0, 0);
      accR[t] = __builtin_amdgcn_mfma_f32_16x16x32_bf16(al, bhR, accR[t], 0, 0, 0);
      accR[t] = __builtin_amdgcn_mfma_f32_16x16x32_bf16(ah, blR, accR[t], 0, 0, 0);
    }
    __syncthreads();
  }
  if (!active) return;
  // epilogue: C/D layout col=lane&15, row=quad*4+reg
  #pragma unroll
  for (int t = 0; t < 8; t++) {
    int n = t * 16 + ml;
    float bL = bl_[n], bR = br_[n];
    #pragma unroll
    for (int r = 0; r < 4; r++) {
      int row = m0 + q * 4 + r;
      outl[(size_t)row * 128 + n] = __float2half(accL[t][r] + bL);
      outr[(size_t)row * 128 + n] = __float2half(accR[t][r] + bR);
    }
  }
}

// ---------------- GATv2 edge pass: 32 lanes/node, fp16 xl/xr ----------------
// Plain-sum softmax (logits O(0.3): exp can't overflow). Empty halves run
// lock-step with the sibling — never use unvalidated scode data as address.
__global__ __launch_bounds__(256) void k_gat(const __half* __restrict__ xl,
                                             const __half* __restrict__ xr,
                                             const int* __restrict__ indptr,
                                             const int4* __restrict__ scode,
                                             const float* __restrict__ tabs,
                                             const float* __restrict__ att,
                                             const float* __restrict__ bias,
                                             float* __restrict__ hout) {
  int wid = (blockIdx.x * 256 + threadIdx.x) >> 6;
  int nw = (gridDim.x * 256) >> 6;
  int lane = threadIdx.x & 63;
  int half = lane >> 5;
  int c = (lane & 31) * 4;  // 4 channels per lane
  const float* T12 = tabs;  // 256 x 128
  float4 v4 = *(const float4*)(tabs + 256 * 128 + c);
  float4 a4 = *(const float4*)(att + c);
  float4 b4 = *(const float4*)(bias + c);
  wid = __builtin_amdgcn_readfirstlane(wid);
  for (int nb = wid * 2; nb < N_NODES; nb += nw * 2) {
    int n = nb + half;
    int beg = indptr[n], end1 = indptr[n + 1] - 1;  // end1 = self-loop slot
    int last = (end1 > beg) ? end1 - 1 : beg;       // clamp (may be unwritten!)
    float4 xrv = h4_to_f4(xr + (size_t)n * 128 + c);
    float denom = 0.f;
    float4 acc = make_float4(0.f, 0.f, 0.f, 0.f);
    float4 els = make_float4(0.f, 0.f, 0.f, 0.f);
    int my_it = (end1 - beg + 3) >> 2;
    int ot = __shfl_xor(my_it, 32, 64);
    int iters = my_it > ot ? my_it : ot;  // wave-uniform
    for (int it = 0; it < iters; it++) {
      int j = beg + it * 4;
      int4 sc4[4]; float4 xlv[4]; float tt[4]; float4 el[4];
      bool val[4];
      #pragma unroll
      for (int u = 0; u < 4; u++) {
        val[u] = (j + u < end1);  // uniform within half
        int jj = val[u] ? j + u : last;
        sc4[u] = scode[jj];
      }
      #pragma unroll
      for (int u = 0; u < 4; u++) {
        int s = val[u] ? sc4[u].x : n;  // NEVER use poison as an address
        xlv[u] = h4_to_f4(xl + (size_t)s * 128 + c);
      }
      #pragma unroll
      for (int u = 0; u < 4; u++) {
        int meta = val[u] ? (sc4[u].y & 255) : 0;
        float ec = val[u] ? __int_as_float(sc4[u].z) : 0.f;
        float4 t12 = *(const float4*)(T12 + (size_t)meta * 128 + c);
        el[u].x = t12.x + ec * v4.x;
        el[u].y = t12.y + ec * v4.y;
        el[u].z = t12.z + ec * v4.z;
        el[u].w = t12.w + ec * v4.w;
        float m0 = xlv[u].x + xrv.x + el[u].x;
        float m1 = xlv[u].y + xrv.y + el[u].y;
        float m2 = xlv[u].z + xrv.z + el[u].z;
        float m3 = xlv[u].w + xrv.w + el[u].w;
        float l0 = m0 > 0.f ? m0 : 0.2f * m0;
        float l1 = m1 > 0.f ? m1 : 0.2f * m1;
        float l2 = m2 > 0.f ? m2 : 0.2f * m2;
        float l3 = m3 > 0.f ? m3 : 0.2f * m3;
        tt[u] = l0 * a4.x + l1 * a4.y + l2 * a4.z + l3 * a4.w;
      }
      // 8 independent half-wave reduction chains (4 per node), 5 steps
      #pragma unroll
      for (int off = 1; off < 32; off <<= 1) {
        tt[0] += __shfl_xor(tt[0], off, 64);
        tt[1] += __shfl_xor(tt[1], off, 64);
        tt[2] += __shfl_xor(tt[2], off, 64);
        tt[3] += __shfl_xor(tt[3], off, 64);
      }
      #pragma unroll
      for (int u = 0; u < 4; u++) {
        float ex = val[u] ? __expf(tt[u]) : 0.f;
        denom += ex;
        acc.x += ex * xlv[u].x;
        acc.y += ex * xlv[u].y;
        acc.z += ex * xlv[u].z;
        acc.w += ex * xlv[u].w;
        els.x += val[u] ? el[u].x : 0.f;
        els.y += val[u] ? el[u].y : 0.f;
        els.z += val[u] ? el[u].z : 0.f;
        els.w += val[u] ? el[u].w : 0.f;
      }
    }
    // self-loop (always present, processed last)
    int cntn = end1 - beg;
    float inv_cnt = 1.0f / (float)(cntn > 0 ? cntn : 1);
    float4 xln = h4_to_f4(xl + (size_t)n * 128 + c);
    float m0 = xln.x + xrv.x + els.x * inv_cnt;
    float m1 = xln.y + xrv.y + els.y * inv_cnt;
    float m2 = xln.z + xrv.z + els.z * inv_cnt;
    float m3 = xln.w + xrv.w + els.w * inv_cnt;
    float l0 = m0 > 0.f ? m0 : 0.2f * m0;
    float l1 = m1 > 0.f ? m1 : 0.2f * m1;
    float l2 = m2 > 0.f ? m2 : 0.2f * m2;
    float l3 = m3 > 0.f ? m3 : 0.2f * m3;
    float ts = l0 * a4.x + l1 * a4.y + l2 * a4.z + l3 * a4.w;
    #pragma unroll
    for (int off = 1; off < 32; off <<= 1) ts += __shfl_xor(ts, off, 64);
    float ex = __expf(ts);
    denom += ex;
    acc.x += ex * xln.x;
    acc.y += ex * xln.y;
    acc.z += ex * xln.z;
    acc.w += ex * xln.w;
    float invd = 1.0f / denom;
    float o0 = acc.x * invd + b4.x;
    float o1 = acc.y * invd + b4.y;
    float o2 = acc.z * invd + b4.z;
    float o3 = acc.w * invd + b4.w;
    float4 o = make_float4(o0 > 0.f ? o0 : 0.f, o1 > 0.f ? o1 : 0.f,
                           o2 > 0.f ? o2 : 0.f, o3 > 0.f ? o3 : 0.f);
    *(float4*)(hout + (size_t)n * 128 + c) = o;
  }
}

// ---------------- readout: global max pool over 20 contiguous nodes --------
__global__ void k_readout(const float* __restrict__ h, float* __restrict__ out) {
  int wid = (blockIdx.x * blockDim.x + threadIdx.x) >> 6;
  int lane = threadIdx.x & 63;
  if (wid >= N_GRAPHS) return;
  int c = lane * 2;
  float m0 = -1e30f, m1 = -1e30f;
  for (int i = 0; i < NPG; i++) {
    const float2 v = *(const float2*)(h + ((size_t)(wid * NPG + i)) * 128 + c);
    m0 = fmaxf(m0, v.x);
    m1 = fmaxf(m1, v.y);
  }
  float2 o; o.x = m0; o.y = m1;
  *(float2*)(out + (size_t)wid * 128 + c) = o;
}

extern "C" void kernel_launch(void* const* d_in, const int* in_sizes, int n_in,
                              void* d_out, int out_size, void* d_ws, size_t ws_size,
                              hipStream_t stream) {
  (void)in_sizes; (void)n_in; (void)out_size; (void)ws_size;
  const float* x        = (const float*)d_in[0];
  const int*   eindex   = (const int*)d_in[1];
  const float* eattr    = (const float*)d_in[2];
  const float* atom_emb = (const float*)d_in[4];
  const float* bond_emb = (const float*)d_in[5];
  const float* bool_emb = (const float*)d_in[6];
  const float* Wn   = (const float*)d_in[7];
  const float* bn   = (const float*)d_in[8];
  const float* We   = (const float*)d_in[9];
  const float* be   = (const float*)d_in[10];
  const float* Wl1  = (const float*)d_in[11];
  const float* bl1  = (const float*)d_in[12];
  const float* Wr1  = (const float*)d_in[13];
  const float* br1  = (const float*)d_in[14];
  const float* Wedge1 = (const float*)d_in[15];
  const float* att1 = (const float*)d_in[16];
  const float* bias1 = (const float*)d_in[17];
  const float* Wl2  = (const float*)d_in[18];
  const float* bl2  = (const float*)d_in[19];
  const float* Wr2  = (const float*)d_in[20];
  const float* br2  = (const float*)d_in[21];
  const float* Wedge2 = (const float*)d_in[22];
  const float* att2 = (const float*)d_in[23];
  const float* bias2 = (const float*)d_in[24];

  const int* srcA = eindex;
  const int* dstA = eindex + N_EDGES;

  char* p = (char*)d_ws;
  auto alloc = [&](size_t bytes) {
    char* r = p;
    p += (bytes + 255) & ~(size_t)255;
    return r;
  };
  float*  h0     = (float*)alloc((size_t)N_NODES * 64 * 4);
  float*  h      = (float*)alloc((size_t)N_NODES * 128 * 4);
  __half* xl     = (__half*)alloc((size_t)N_NODES * 128 * 2);
  __half* xrb    = (__half*)alloc((size_t)N_NODES * 128 * 2);
  int*    cnt    = (int*)alloc((size_t)N_NODES * 4);
  int*    indptr = (int*)alloc((size_t)(N_NODES + 1) * 4);
  int*    cursor = (int*)alloc((size_t)N_NODES * 4);
  int4*   scode  = (int4*)alloc((size_t)(N_EDGES + N_NODES) * 16);
  float*  tabs   = (float*)alloc((size_t)2 * TAB_STRIDE * 4);
  unsigned short* wfrag = (unsigned short*)alloc((size_t)(2 * F1 + 2 * F2) * 2);
  int*    bsum   = (int*)alloc((size_t)SCAN_NB * 4);

  hipMemsetAsync(cnt, 0, (size_t)N_NODES * 4, stream);

  // fused prologue: encode | hist | tabs | prep
  k_prologue<<<NB_ENC + NB_HIST + 1 + 24, 256, 0, stream>>>(
      x, atom_emb, bool_emb, Wn, bn, h0, dstA, cnt,
      Wedge1, Wedge2, bond_emb, We, be, tabs,
      Wl1, Wr1, Wl2, Wr2, wfrag);
  k_scan1<<<SCAN_NB, 256, 0, stream>>>(cnt, bsum);
  k_scan2<<<1, 256, 0, stream>>>(bsum);
  k_scan3<<<SCAN_NB, 256, 0, stream>>>(cnt, bsum, indptr, cursor);
  k_fill<<<(N_EDGES + 255) / 256, 256, 0, stream>>>(srcA, dstA, eattr, cursor, scode);

  const unsigned short* f_l1 = wfrag;
  const unsigned short* f_r1 = wfrag + F1;
  const unsigned short* f_l2 = wfrag + 2 * F1;
  const unsigned short* f_r2 = wfrag + 2 * F1 + F2;

  const int GB2 = (N_NODES / 16 + 3) / 4;  // 1563 blocks of 4 waves

  // layer 1 (K=52 zero-padded to 64)
  k_gemm2m<64><<<GB2, 256, 0, stream>>>(h0, f_l1, f_r1, bl1, br1, xl, xrb);
  k_gat<<<2048, 256, 0, stream>>>(xl, xrb, indptr, scode, tabs, att1, bias1, h);

  // layer 2 (K=128)
  k_gemm2m<128><<<GB2, 256, 0, stream>>>(h, f_l2, f_r2, bl2, br2, xl, xrb);
  k_gat<<<2048, 256, 0, stream>>>(xl, xrb, indptr, scode, tabs + TAB_STRIDE, att2, bias2, h);

  // layer 3 (shared weights with layer 2)
  k_gemm2m<128><<<GB2, 256, 0, stream>>>(h, f_l2, f_r2, bl2, br2, xl, xrb);
  k_gat<<<2048, 256, 0, stream>>>(xl, xrb, indptr, scode, tabs + TAB_STRIDE, att2, bias2, h);

  k_readout<<<(N_GRAPHS * 64 + 255) / 256, 256, 0, stream>>>(h, (float*)d_out);
}

// Round 14
// 420.635 us; speedup vs baseline: 1.2733x; 1.0259x over previous
//
#include <hip/hip_runtime.h>
#include <hip/hip_fp16.h>

#define N_NODES 100000
#define N_EDGES 400000
#define N_GRAPHS 5000
#define NPG 20
#define SCAN_NB 256
#define SCAN_CHUNK ((N_NODES + SCAN_NB - 1) / SCAN_NB)  // 391
#define TAB_STRIDE (256 * 128 + 128)  // T12[256][128] + v[128]
#define F1 8192   // ushorts per K=64 frag array (1024 frags * 8, fp16)
#define F2 16384  // ushorts per K=128 frag array (2048 frags * 8, fp16)
#define NB_ENC ((N_NODES + 255) / 256)   // 391
#define NB_HIST ((N_EDGES + 255) / 256)  // 1563

typedef __attribute__((ext_vector_type(8))) _Float16 f16x8;
typedef __attribute__((ext_vector_type(4))) float f32x4;

__device__ __forceinline__ float4 h4_to_f4(const __half* p) {
  const __half2* q = (const __half2*)p;
  float2 a = __half22float2(q[0]);
  float2 b = __half22float2(q[1]);
  return make_float4(a.x, a.y, b.x, b.y);
}

// ---------------- fused prologue: encode_nodes | hist | tabs | prep ---------
__global__ __launch_bounds__(256) void k_prologue(
    const float* __restrict__ x, const float* __restrict__ atom_emb,
    const float* __restrict__ bool_emb, const float* __restrict__ Wn,
    const float* __restrict__ bn, float* __restrict__ h0,
    const int* __restrict__ dst, int* __restrict__ cnt,
    const float* __restrict__ Wedge1, const float* __restrict__ Wedge2,
    const float* __restrict__ bond_emb, const float* __restrict__ We,
    const float* __restrict__ be, float* __restrict__ tabs,
    const float* __restrict__ Wl1, const float* __restrict__ Wr1,
    const float* __restrict__ Wl2, const float* __restrict__ Wr2,
    unsigned short* __restrict__ fr) {
  int b = blockIdx.x, tid = threadIdx.x;
  if (b < NB_ENC) {
    // ---- node encoder: h0[N,64] (cols 52..63 zero) ----
    int n = b * 256 + tid;
    if (n >= N_NODES) return;
    const float* xr = x + (size_t)n * 14;
    float* h = h0 + (size_t)n * 64;
    int ai = (int)xr[0];
    #pragma unroll
    for (int j = 0; j < 16; j++) h[j] = atom_emb[ai * 16 + j];
    float xc[10];
    #pragma unroll
    for (int k = 0; k < 10; k++) xc[k] = xr[1 + k];
    #pragma unroll
    for (int c = 0; c < 30; c++) {
      float s = bn[c];
      #pragma unroll
      for (int k = 0; k < 10; k++) s += xc[k] * Wn[k * 30 + c];
      h[16 + c] = s;
    }
    #pragma unroll
    for (int t = 0; t < 3; t++) {
      int bb = (int)xr[11 + t];
      h[46 + 2 * t]     = bool_emb[2 * bb];
      h[46 + 2 * t + 1] = bool_emb[2 * bb + 1];
    }
    #pragma unroll
    for (int j = 52; j < 64; j++) h[j] = 0.0f;
  } else if (b < NB_ENC + NB_HIST) {
    // ---- in-degree histogram ----
    int e = (b - NB_ENC) * 256 + tid;
    if (e >= N_EDGES) return;
    atomicAdd(cnt + dst[e], 1);
  } else if (b == NB_ENC + NB_HIST) {
    // ---- fused logit table: T12[combo*32+bi], v ----
    int s = tid >> 7, c = tid & 127;
    const float* W = s ? Wedge2 : Wedge1;
    float* T12 = tabs + s * TAB_STRIDE;
    float* v   = T12 + 256 * 128;
    float w8 = W[8 * 128 + c], w9 = W[9 * 128 + c];
    v[c] = We[0] * w8 + We[1] * w9;
    float cst = be[0] * w8 + be[1] * w9;
    float bond[22];
    for (int bb = 0; bb < 22; bb++) {
      float acc = 0.f;
      #pragma unroll
      for (int k = 0; k < 8; k++) acc += bond_emb[bb * 8 + k] * W[k * 128 + c];
      bond[bb] = acc;
    }
    for (int combo = 0; combo < 8; combo++) {
      float t2 = cst;
      #pragma unroll
      for (int tt = 0; tt < 3; tt++) {
        int bt = (combo >> tt) & 1;
        t2 += bool_emb[bt * 2 + 0] * W[(10 + 2 * tt + 0) * 128 + c];
        t2 += bool_emb[bt * 2 + 1] * W[(10 + 2 * tt + 1) * 128 + c];
      }
      for (int bb = 0; bb < 22; bb++)
        T12[(combo * 32 + bb) * 128 + c] = bond[bb] + t2;
    }
  } else {
    // ---- W -> MFMA B-fragment prep (fp16, 8 halves = 16 B per frag) ----
    int g = (b - (NB_ENC + NB_HIST + 1)) * 256 + tid;
    const float* W; int K; unsigned short* base; int fl;
    if (g < 1024)      { W = Wl1; K = 52;  base = fr;               fl = g; }
    else if (g < 2048) { W = Wr1; K = 52;  base = fr + F1;          fl = g - 1024; }
    else if (g < 4096) { W = Wl2; K = 128; base = fr + 2 * F1;      fl = g - 2048; }
    else if (g < 6144) { W = Wr2; K = 128; base = fr + 2 * F1 + F2; fl = g - 4096; }
    else return;
    int l = fl & 63, ctn = fl >> 6;
    int tn = ctn & 7, c = ctn >> 3;
    int n = tn * 16 + (l & 15);
    int kb = c * 32 + (l >> 4) * 8;
    unsigned h8[8];
    #pragma unroll
    for (int j = 0; j < 8; j++) {
      int k = kb + j;
      float v = (k < K) ? W[(size_t)k * 128 + n] : 0.f;
      __half hv = __float2half(v);
      h8[j] = (unsigned)*(unsigned short*)&hv;
    }
    uint4 hv4 = make_uint4(h8[0] | (h8[1] << 16), h8[2] | (h8[3] << 16),
                           h8[4] | (h8[5] << 16), h8[6] | (h8[7] << 16));
    *(uint4*)(base + (size_t)fl * 8) = hv4;
  }
}

// ---------------- hierarchical scan over (cnt[n]+1), 3 phases ---------------
__global__ __launch_bounds__(256) void k_scan1(const int* __restrict__ cnt,
                                               int* __restrict__ bsum) {
  __shared__ int red[256];
  int b = blockIdx.x, t = threadIdx.x;
  int beg = b * SCAN_CHUNK;
  int end = beg + SCAN_CHUNK; if (end > N_NODES) end = N_NODES;
  int s = 0;
  for (int i = beg + t; i < end; i += 256) s += cnt[i] + 1;
  red[t] = s;
  __syncthreads();
  for (int off = 128; off > 0; off >>= 1) {
    if (t < off) red[t] += red[t + off];
    __syncthreads();
  }
  if (t == 0) bsum[b] = red[0];
}

__global__ __launch_bounds__(256) void k_scan2(int* __restrict__ bsum) {
  __shared__ int sh[256];
  int t = threadIdx.x;
  sh[t] = bsum[t];
  __syncthreads();
  for (int off = 1; off < 256; off <<= 1) {
    int v = (t >= off) ? sh[t - off] : 0;
    __syncthreads();
    sh[t] += v;
    __syncthreads();
  }
  bsum[t] = (t > 0) ? sh[t - 1] : 0;  // exclusive
}

__global__ __launch_bounds__(256) void k_scan3(const int* __restrict__ cnt,
                                               const int* __restrict__ bsum,
                                               int* __restrict__ indptr,
                                               int* __restrict__ cursor) {
  __shared__ int sh[256];
  __shared__ int carry;
  int b = blockIdx.x, t = threadIdx.x;
  int beg = b * SCAN_CHUNK;
  int end = beg + SCAN_CHUNK; if (end > N_NODES) end = N_NODES;
  if (t == 0) carry = bsum[b];
  __syncthreads();
  for (int base = beg; base < end; base += 256) {
    int i = base + t;
    int v = (i < end) ? cnt[i] + 1 : 0;
    sh[t] = v;
    __syncthreads();
    for (int off = 1; off < 256; off <<= 1) {
      int u = (t >= off) ? sh[t - off] : 0;
      __syncthreads();
      sh[t] += u;
      __syncthreads();
    }
    int excl = sh[t] - v;
    if (i < end) {
      int val = carry + excl;
      indptr[i] = val;
      cursor[i] = val;
    }
    __syncthreads();
    if (t == 255) carry += sh[255];
    __syncthreads();
  }
  if (b == 0 && t == 0) indptr[N_NODES] = N_EDGES + N_NODES;
}

// ---------------- CSR fill: ordinary edges into slots [beg, end-1) ----------
__global__ void k_fill(const int* __restrict__ srcA,
                       const int* __restrict__ dst,
                       const float* __restrict__ eattr,
                       int* __restrict__ cursor,
                       int4* __restrict__ scode) {
  int e = blockIdx.x * blockDim.x + threadIdx.x;
  if (e >= N_EDGES) return;
  const float* r = eattr + (size_t)e * 5;
  int bi = (int)r[0];
  float ec = r[1];
  int combo = (int)r[2] + 2 * (int)r[3] + 4 * (int)r[4];
  int meta = bi | (combo << 5);
  int d = dst[e];
  int p = atomicAdd(&cursor[d], 1);
  scode[p] = make_int4(srcA[e], meta, __float_as_int(ec), 0);
}

// ---------------- MFMA dual GEMM, M=16/wave, LDS-staged fp16 B --------------
// Single fp16 MFMA per tile per W (fp32 accumulate): accuracy ~1e-4 per
// element, same scale as the fp16 output storage. 4 waves/block share each
// 16 KB chunk stage (L/R, 8 KB each).
template <int KPAD>
__global__ __launch_bounds__(256, 4) void k_gemm2m(const float* __restrict__ A,
                                                   const unsigned short* __restrict__ WfL,
                                                   const unsigned short* __restrict__ WfR,
                                                   const float* __restrict__ bl_,
                                                   const float* __restrict__ br_,
                                                   __half* __restrict__ outl,
                                                   __half* __restrict__ outr) {
  __shared__ unsigned short Bs[2][4096];  // L, R (8 KB each)
  const int tid = threadIdx.x;
  const int wv = tid >> 6, lane = tid & 63;
  const int tw = blockIdx.x * 4 + wv;
  const bool active = (tw < N_NODES / 16);  // tail waves stay for barriers
  const int ml = lane & 15, q = lane >> 4;
  const int m0 = active ? tw * 16 : 0;
  f32x4 accL[8], accR[8];
  #pragma unroll
  for (int t = 0; t < 8; t++) {
    accL[t] = (f32x4){0.f, 0.f, 0.f, 0.f};
    accR[t] = (f32x4){0.f, 0.f, 0.f, 0.f};
  }
  const float* ar0 = A + (size_t)(m0 + ml) * KPAD + q * 8;
  constexpr int NC = KPAD / 32;
  for (int c = 0; c < NC; c++) {
    // stage chunk: 512 fp16 frags (16 B each) per W
    #pragma unroll
    for (int i0 = 0; i0 < 512; i0 += 256) {
      int i = i0 + tid;
      size_t g = ((size_t)c * 512 + i) * 8;
      *(uint4*)(&Bs[0][i * 8]) = *(const uint4*)(WfL + g);
      *(uint4*)(&Bs[1][i * 8]) = *(const uint4*)(WfR + g);
    }
    __syncthreads();
    float4 x0 = *(const float4*)(ar0 + c * 32);
    float4 x1 = *(const float4*)(ar0 + c * 32 + 4);
    float av[8] = {x0.x, x0.y, x0.z, x0.w, x1.x, x1.y, x1.z, x1.w};
    f16x8 a;
    #pragma unroll
    for (int j = 0; j < 8; j++) a[j] = (_Float16)av[j];
    #pragma unroll
    for (int t = 0; t < 8; t++) {
      int idx = (t * 64 + lane) * 8;
      f16x8 bL = *(const f16x8*)(&Bs[0][idx]);
      f16x8 bR = *(const f16x8*)(&Bs[1][idx]);
      accL[t] = __builtin_amdgcn_mfma_f32_16x16x32_f16(a, bL, accL[t], 0, 0, 0);
      accR[t] = __builtin_amdgcn_mfma_f32_16x16x32_f16(a, bR, accR[t], 0, 0, 0);
    }
    __syncthreads();
  }
  if (!active) return;
  // epilogue: C/D layout col=lane&15, row=quad*4+reg
  #pragma unroll
  for (int t = 0; t < 8; t++) {
    int n = t * 16 + ml;
    float bL = bl_[n], bR = br_[n];
    #pragma unroll
    for (int r = 0; r < 4; r++) {
      int row = m0 + q * 4 + r;
      outl[(size_t)row * 128 + n] = __float2half(accL[t][r] + bL);
      outr[(size_t)row * 128 + n] = __float2half(accR[t][r] + bR);
    }
  }
}

// ---------------- GATv2 edge pass: 32 lanes/node, fp16 xl/xr ----------------
// Plain-sum softmax (logits O(0.3): exp can't overflow). Empty halves run
// lock-step with the sibling — never use unvalidated scode data as address.
__global__ __launch_bounds__(256) void k_gat(const __half* __restrict__ xl,
                                             const __half* __restrict__ xr,
                                             const int* __restrict__ indptr,
                                             const int4* __restrict__ scode,
                                             const float* __restrict__ tabs,
                                             const float* __restrict__ att,
                                             const float* __restrict__ bias,
                                             float* __restrict__ hout) {
  int wid = (blockIdx.x * 256 + threadIdx.x) >> 6;
  int nw = (gridDim.x * 256) >> 6;
  int lane = threadIdx.x & 63;
  int half = lane >> 5;
  int c = (lane & 31) * 4;  // 4 channels per lane
  const float* T12 = tabs;  // 256 x 128
  float4 v4 = *(const float4*)(tabs + 256 * 128 + c);
  float4 a4 = *(const float4*)(att + c);
  float4 b4 = *(const float4*)(bias + c);
  wid = __builtin_amdgcn_readfirstlane(wid);
  for (int nb = wid * 2; nb < N_NODES; nb += nw * 2) {
    int n = nb + half;
    int beg = indptr[n], end1 = indptr[n + 1] - 1;  // end1 = self-loop slot
    int last = (end1 > beg) ? end1 - 1 : beg;       // clamp (may be unwritten!)
    float4 xrv = h4_to_f4(xr + (size_t)n * 128 + c);
    float denom = 0.f;
    float4 acc = make_float4(0.f, 0.f, 0.f, 0.f);
    float4 els = make_float4(0.f, 0.f, 0.f, 0.f);
    int my_it = (end1 - beg + 3) >> 2;
    int ot = __shfl_xor(my_it, 32, 64);
    int iters = my_it > ot ? my_it : ot;  // wave-uniform
    for (int it = 0; it < iters; it++) {
      int j = beg + it * 4;
      int4 sc4[4]; float4 xlv[4]; float tt[4]; float4 el[4];
      bool val[4];
      #pragma unroll
      for (int u = 0; u < 4; u++) {
        val[u] = (j + u < end1);  // uniform within half
        int jj = val[u] ? j + u : last;
        sc4[u] = scode[jj];
      }
      #pragma unroll
      for (int u = 0; u < 4; u++) {
        int s = val[u] ? sc4[u].x : n;  // NEVER use poison as an address
        xlv[u] = h4_to_f4(xl + (size_t)s * 128 + c);
      }
      #pragma unroll
      for (int u = 0; u < 4; u++) {
        int meta = val[u] ? (sc4[u].y & 255) : 0;
        float ec = val[u] ? __int_as_float(sc4[u].z) : 0.f;
        float4 t12 = *(const float4*)(T12 + (size_t)meta * 128 + c);
        el[u].x = t12.x + ec * v4.x;
        el[u].y = t12.y + ec * v4.y;
        el[u].z = t12.z + ec * v4.z;
        el[u].w = t12.w + ec * v4.w;
        float m0 = xlv[u].x + xrv.x + el[u].x;
        float m1 = xlv[u].y + xrv.y + el[u].y;
        float m2 = xlv[u].z + xrv.z + el[u].z;
        float m3 = xlv[u].w + xrv.w + el[u].w;
        float l0 = m0 > 0.f ? m0 : 0.2f * m0;
        float l1 = m1 > 0.f ? m1 : 0.2f * m1;
        float l2 = m2 > 0.f ? m2 : 0.2f * m2;
        float l3 = m3 > 0.f ? m3 : 0.2f * m3;
        tt[u] = l0 * a4.x + l1 * a4.y + l2 * a4.z + l3 * a4.w;
      }
      // 8 independent half-wave reduction chains (4 per node), 5 steps
      #pragma unroll
      for (int off = 1; off < 32; off <<= 1) {
        tt[0] += __shfl_xor(tt[0], off, 64);
        tt[1] += __shfl_xor(tt[1], off, 64);
        tt[2] += __shfl_xor(tt[2], off, 64);
        tt[3] += __shfl_xor(tt[3], off, 64);
      }
      #pragma unroll
      for (int u = 0; u < 4; u++) {
        float ex = val[u] ? __expf(tt[u]) : 0.f;
        denom += ex;
        acc.x += ex * xlv[u].x;
        acc.y += ex * xlv[u].y;
        acc.z += ex * xlv[u].z;
        acc.w += ex * xlv[u].w;
        els.x += val[u] ? el[u].x : 0.f;
        els.y += val[u] ? el[u].y : 0.f;
        els.z += val[u] ? el[u].z : 0.f;
        els.w += val[u] ? el[u].w : 0.f;
      }
    }
    // self-loop (always present, processed last)
    int cntn = end1 - beg;
    float inv_cnt = 1.0f / (float)(cntn > 0 ? cntn : 1);
    float4 xln = h4_to_f4(xl + (size_t)n * 128 + c);
    float m0 = xln.x + xrv.x + els.x * inv_cnt;
    float m1 = xln.y + xrv.y + els.y * inv_cnt;
    float m2 = xln.z + xrv.z + els.z * inv_cnt;
    float m3 = xln.w + xrv.w + els.w * inv_cnt;
    float l0 = m0 > 0.f ? m0 : 0.2f * m0;
    float l1 = m1 > 0.f ? m1 : 0.2f * m1;
    float l2 = m2 > 0.f ? m2 : 0.2f * m2;
    float l3 = m3 > 0.f ? m3 : 0.2f * m3;
    float ts = l0 * a4.x + l1 * a4.y + l2 * a4.z + l3 * a4.w;
    #pragma unroll
    for (int off = 1; off < 32; off <<= 1) ts += __shfl_xor(ts, off, 64);
    float ex = __expf(ts);
    denom += ex;
    acc.x += ex * xln.x;
    acc.y += ex * xln.y;
    acc.z += ex * xln.z;
    acc.w += ex * xln.w;
    float invd = 1.0f / denom;
    float o0 = acc.x * invd + b4.x;
    float o1 = acc.y * invd + b4.y;
    float o2 = acc.z * invd + b4.z;
    float o3 = acc.w * invd + b4.w;
    float4 o = make_float4(o0 > 0.f ? o0 : 0.f, o1 > 0.f ? o1 : 0.f,
                           o2 > 0.f ? o2 : 0.f, o3 > 0.f ? o3 : 0.f);
    *(float4*)(hout + (size_t)n * 128 + c) = o;
  }
}

// ---------------- readout: global max pool over 20 contiguous nodes --------
__global__ void k_readout(const float* __restrict__ h, float* __restrict__ out) {
  int wid = (blockIdx.x * blockDim.x + threadIdx.x) >> 6;
  int lane = threadIdx.x & 63;
  if (wid >= N_GRAPHS) return;
  int c = lane * 2;
  float m0 = -1e30f, m1 = -1e30f;
  for (int i = 0; i < NPG; i++) {
    const float2 v = *(const float2*)(h + ((size_t)(wid * NPG + i)) * 128 + c);
    m0 = fmaxf(m0, v.x);
    m1 = fmaxf(m1, v.y);
  }
  float2 o; o.x = m0; o.y = m1;
  *(float2*)(out + (size_t)wid * 128 + c) = o;
}

extern "C" void kernel_launch(void* const* d_in, const int* in_sizes, int n_in,
                              void* d_out, int out_size, void* d_ws, size_t ws_size,
                              hipStream_t stream) {
  (void)in_sizes; (void)n_in; (void)out_size; (void)ws_size;
  const float* x        = (const float*)d_in[0];
  const int*   eindex   = (const int*)d_in[1];
  const float* eattr    = (const float*)d_in[2];
  const float* atom_emb = (const float*)d_in[4];
  const float* bond_emb = (const float*)d_in[5];
  const float* bool_emb = (const float*)d_in[6];
  const float* Wn   = (const float*)d_in[7];
  const float* bn   = (const float*)d_in[8];
  const float* We   = (const float*)d_in[9];
  const float* be   = (const float*)d_in[10];
  const float* Wl1  = (const float*)d_in[11];
  const float* bl1  = (const float*)d_in[12];
  const float* Wr1  = (const float*)d_in[13];
  const float* br1  = (const float*)d_in[14];
  const float* Wedge1 = (const float*)d_in[15];
  const float* att1 = (const float*)d_in[16];
  const float* bias1 = (const float*)d_in[17];
  const float* Wl2  = (const float*)d_in[18];
  const float* bl2  = (const float*)d_in[19];
  const float* Wr2  = (const float*)d_in[20];
  const float* br2  = (const float*)d_in[21];
  const float* Wedge2 = (const float*)d_in[22];
  const float* att2 = (const float*)d_in[23];
  const float* bias2 = (const float*)d_in[24];

  const int* srcA = eindex;
  const int* dstA = eindex + N_EDGES;

  char* p = (char*)d_ws;
  auto alloc = [&](size_t bytes) {
    char* r = p;
    p += (bytes + 255) & ~(size_t)255;
    return r;
  };
  float*  h0     = (float*)alloc((size_t)N_NODES * 64 * 4);
  float*  h      = (float*)alloc((size_t)N_NODES * 128 * 4);
  __half* xl     = (__half*)alloc((size_t)N_NODES * 128 * 2);
  __half* xrb    = (__half*)alloc((size_t)N_NODES * 128 * 2);
  int*    cnt    = (int*)alloc((size_t)N_NODES * 4);
  int*    indptr = (int*)alloc((size_t)(N_NODES + 1) * 4);
  int*    cursor = (int*)alloc((size_t)N_NODES * 4);
  int4*   scode  = (int4*)alloc((size_t)(N_EDGES + N_NODES) * 16);
  float*  tabs   = (float*)alloc((size_t)2 * TAB_STRIDE * 4);
  unsigned short* wfrag = (unsigned short*)alloc((size_t)(2 * F1 + 2 * F2) * 2);
  int*    bsum   = (int*)alloc((size_t)SCAN_NB * 4);

  hipMemsetAsync(cnt, 0, (size_t)N_NODES * 4, stream);

  // fused prologue: encode | hist | tabs | prep
  k_prologue<<<NB_ENC + NB_HIST + 1 + 24, 256, 0, stream>>>(
      x, atom_emb, bool_emb, Wn, bn, h0, dstA, cnt,
      Wedge1, Wedge2, bond_emb, We, be, tabs,
      Wl1, Wr1, Wl2, Wr2, wfrag);
  k_scan1<<<SCAN_NB, 256, 0, stream>>>(cnt, bsum);
  k_scan2<<<1, 256, 0, stream>>>(bsum);
  k_scan3<<<SCAN_NB, 256, 0, stream>>>(cnt, bsum, indptr, cursor);
  k_fill<<<(N_EDGES + 255) / 256, 256, 0, stream>>>(srcA, dstA, eattr, cursor, scode);

  const unsigned short* f_l1 = wfrag;
  const unsigned short* f_r1 = wfrag + F1;
  const unsigned short* f_l2 = wfrag + 2 * F1;
  const unsigned short* f_r2 = wfrag + 2 * F1 + F2;

  const int GB2 = (N_NODES / 16 + 3) / 4;  // 1563 blocks of 4 waves

  // layer 1 (K=52 zero-padded to 64)
  k_gemm2m<64><<<GB2, 256, 0, stream>>>(h0, f_l1, f_r1, bl1, br1, xl, xrb);
  k_gat<<<2048, 256, 0, stream>>>(xl, xrb, indptr, scode, tabs, att1, bias1, h);

  // layer 2 (K=128)
  k_gemm2m<128><<<GB2, 256, 0, stream>>>(h, f_l2, f_r2, bl2, br2, xl, xrb);
  k_gat<<<2048, 256, 0, stream>>>(xl, xrb, indptr, scode, tabs + TAB_STRIDE, att2, bias2, h);

  // layer 3 (shared weights with layer 2)
  k_gemm2m<128><<<GB2, 256, 0, stream>>>(h, f_l2, f_r2, bl2, br2, xl, xrb);
  k_gat<<<2048, 256, 0, stream>>>(xl, xrb, indptr, scode, tabs + TAB_STRIDE, att2, bias2, h);

  k_readout<<<(N_GRAPHS * 64 + 255) / 256, 256, 0, stream>>>(h, (float*)d_out);
}

// Round 16
// 389.005 us; speedup vs baseline: 1.3769x; 1.0813x over previous
//
#include <hip/hip_runtime.h>
#include <hip/hip_fp16.h>

#define N_NODES 100000
#define N_EDGES 400000
#define N_GRAPHS 5000
#define NPG 20
#define SCAN_NB 256
#define SCAN_CHUNK ((N_NODES + SCAN_NB - 1) / SCAN_NB)  // 391
#define TAB_STRIDE (256 * 128 + 128)  // halves: T12[256][128] + v[128]
#define F1 8192   // ushorts per K=64 frag array (1024 frags * 8, fp16)
#define F2 16384  // ushorts per K=128 frag array (2048 frags * 8, fp16)
#define NB_ENC ((N_NODES + 255) / 256)   // 391
#define NB_HIST ((N_EDGES + 255) / 256)  // 1563

typedef __attribute__((ext_vector_type(8))) _Float16 f16x8;
typedef __attribute__((ext_vector_type(2))) _Float16 h2;
typedef __attribute__((ext_vector_type(4))) float f32x4;

// ---------------- fused prologue: encode_nodes | hist | tabs | prep ---------
__global__ __launch_bounds__(256) void k_prologue(
    const float* __restrict__ x, const float* __restrict__ atom_emb,
    const float* __restrict__ bool_emb, const float* __restrict__ Wn,
    const float* __restrict__ bn, __half* __restrict__ h0,
    const int* __restrict__ dst, int* __restrict__ cnt,
    const float* __restrict__ Wedge1, const float* __restrict__ Wedge2,
    const float* __restrict__ bond_emb, const float* __restrict__ We,
    const float* __restrict__ be, __half* __restrict__ tabs,
    const float* __restrict__ Wl1, const float* __restrict__ Wr1,
    const float* __restrict__ Wl2, const float* __restrict__ Wr2,
    unsigned short* __restrict__ fr) {
  int b = blockIdx.x, tid = threadIdx.x;
  if (b < NB_ENC) {
    // ---- node encoder: h0[N,64] fp16 (cols 52..63 zero) ----
    int n = b * 256 + tid;
    if (n >= N_NODES) return;
    const float* xr = x + (size_t)n * 14;
    __half* h = h0 + (size_t)n * 64;
    int ai = (int)xr[0];
    #pragma unroll
    for (int j = 0; j < 16; j++) h[j] = __float2half(atom_emb[ai * 16 + j]);
    float xc[10];
    #pragma unroll
    for (int k = 0; k < 10; k++) xc[k] = xr[1 + k];
    #pragma unroll
    for (int c = 0; c < 30; c++) {
      float s = bn[c];
      #pragma unroll
      for (int k = 0; k < 10; k++) s += xc[k] * Wn[k * 30 + c];
      h[16 + c] = __float2half(s);
    }
    #pragma unroll
    for (int t = 0; t < 3; t++) {
      int bb = (int)xr[11 + t];
      h[46 + 2 * t]     = __float2half(bool_emb[2 * bb]);
      h[46 + 2 * t + 1] = __float2half(bool_emb[2 * bb + 1]);
    }
    #pragma unroll
    for (int j = 52; j < 64; j++) h[j] = __float2half(0.0f);
  } else if (b < NB_ENC + NB_HIST) {
    // ---- in-degree histogram ----
    int e = (b - NB_ENC) * 256 + tid;
    if (e >= N_EDGES) return;
    atomicAdd(cnt + dst[e], 1);
  } else if (b == NB_ENC + NB_HIST) {
    // ---- fused logit table (fp16): T12[combo*32+bi], v; rows 22..31 = 0 ----
    int s = tid >> 7, c = tid & 127;
    const float* W = s ? Wedge2 : Wedge1;
    __half* T12 = tabs + (size_t)s * TAB_STRIDE;
    __half* v   = T12 + 256 * 128;
    float w8 = W[8 * 128 + c], w9 = W[9 * 128 + c];
    v[c] = __float2half(We[0] * w8 + We[1] * w9);
    float cst = be[0] * w8 + be[1] * w9;
    float bond[22];
    for (int bb = 0; bb < 22; bb++) {
      float acc = 0.f;
      #pragma unroll
      for (int k = 0; k < 8; k++) acc += bond_emb[bb * 8 + k] * W[k * 128 + c];
      bond[bb] = acc;
    }
    for (int combo = 0; combo < 8; combo++) {
      float t2 = cst;
      #pragma unroll
      for (int tt = 0; tt < 3; tt++) {
        int bt = (combo >> tt) & 1;
        t2 += bool_emb[bt * 2 + 0] * W[(10 + 2 * tt + 0) * 128 + c];
        t2 += bool_emb[bt * 2 + 1] * W[(10 + 2 * tt + 1) * 128 + c];
      }
      for (int bb = 0; bb < 22; bb++)
        T12[(combo * 32 + bb) * 128 + c] = __float2half(bond[bb] + t2);
      for (int bb = 22; bb < 32; bb++)   // incl. row 255 = zero (invalid slots)
        T12[(combo * 32 + bb) * 128 + c] = __float2half(0.f);
    }
  } else {
    // ---- W -> MFMA B-fragment prep (fp16, 8 halves = 16 B per frag) ----
    int g = (b - (NB_ENC + NB_HIST + 1)) * 256 + tid;
    const float* W; int K; unsigned short* base; int fl;
    if (g < 1024)      { W = Wl1; K = 52;  base = fr;               fl = g; }
    else if (g < 2048) { W = Wr1; K = 52;  base = fr + F1;          fl = g - 1024; }
    else if (g < 4096) { W = Wl2; K = 128; base = fr + 2 * F1;      fl = g - 2048; }
    else if (g < 6144) { W = Wr2; K = 128; base = fr + 2 * F1 + F2; fl = g - 4096; }
    else return;
    int l = fl & 63, ctn = fl >> 6;
    int tn = ctn & 7, c = ctn >> 3;
    int n = tn * 16 + (l & 15);
    int kb = c * 32 + (l >> 4) * 8;
    unsigned h8[8];
    #pragma unroll
    for (int j = 0; j < 8; j++) {
      int k = kb + j;
      float v = (k < K) ? W[(size_t)k * 128 + n] : 0.f;
      __half hv = __float2half(v);
      h8[j] = (unsigned)*(unsigned short*)&hv;
    }
    uint4 hv4 = make_uint4(h8[0] | (h8[1] << 16), h8[2] | (h8[3] << 16),
                           h8[4] | (h8[5] << 16), h8[6] | (h8[7] << 16));
    *(uint4*)(base + (size_t)fl * 8) = hv4;
  }
}

// ---------------- hierarchical scan over (cnt[n]+1), 3 phases ---------------
__global__ __launch_bounds__(256) void k_scan1(const int* __restrict__ cnt,
                                               int* __restrict__ bsum) {
  __shared__ int red[256];
  int b = blockIdx.x, t = threadIdx.x;
  int beg = b * SCAN_CHUNK;
  int end = beg + SCAN_CHUNK; if (end > N_NODES) end = N_NODES;
  int s = 0;
  for (int i = beg + t; i < end; i += 256) s += cnt[i] + 1;
  red[t] = s;
  __syncthreads();
  for (int off = 128; off > 0; off >>= 1) {
    if (t < off) red[t] += red[t + off];
    __syncthreads();
  }
  if (t == 0) bsum[b] = red[0];
}

__global__ __launch_bounds__(256) void k_scan2(int* __restrict__ bsum) {
  __shared__ int sh[256];
  int t = threadIdx.x;
  sh[t] = bsum[t];
  __syncthreads();
  for (int off = 1; off < 256; off <<= 1) {
    int v = (t >= off) ? sh[t - off] : 0;
    __syncthreads();
    sh[t] += v;
    __syncthreads();
  }
  bsum[t] = (t > 0) ? sh[t - 1] : 0;  // exclusive
}

__global__ __launch_bounds__(256) void k_scan3(const int* __restrict__ cnt,
                                               const int* __restrict__ bsum,
                                               int* __restrict__ indptr,
                                               int* __restrict__ cursor) {
  __shared__ int sh[256];
  __shared__ int carry;
  int b = blockIdx.x, t = threadIdx.x;
  int beg = b * SCAN_CHUNK;
  int end = beg + SCAN_CHUNK; if (end > N_NODES) end = N_NODES;
  if (t == 0) carry = bsum[b];
  __syncthreads();
  for (int base = beg; base < end; base += 256) {
    int i = base + t;
    int v = (i < end) ? cnt[i] + 1 : 0;
    sh[t] = v;
    __syncthreads();
    for (int off = 1; off < 256; off <<= 1) {
      int u = (t >= off) ? sh[t - off] : 0;
      __syncthreads();
      sh[t] += u;
      __syncthreads();
    }
    int excl = sh[t] - v;
    if (i < end) {
      int val = carry + excl;
      indptr[i] = val;
      cursor[i] = val;
    }
    __syncthreads();
    if (t == 255) carry += sh[255];
    __syncthreads();
  }
  if (b == 0 && t == 0) indptr[N_NODES] = N_EDGES + N_NODES;
}

// ---------------- CSR fill: ordinary edges into slots [beg, end-1) ----------
__global__ void k_fill(const int* __restrict__ srcA,
                       const int* __restrict__ dst,
                       const float* __restrict__ eattr,
                       int* __restrict__ cursor,
                       int4* __restrict__ scode) {
  int e = blockIdx.x * blockDim.x + threadIdx.x;
  if (e >= N_EDGES) return;
  const float* r = eattr + (size_t)e * 5;
  int bi = (int)r[0];
  float ec = r[1];
  int combo = (int)r[2] + 2 * (int)r[3] + 4 * (int)r[4];
  int meta = bi | (combo << 5);
  int d = dst[e];
  int p = atomicAdd(&cursor[d], 1);
  scode[p] = make_int4(srcA[e], meta, __float_as_int(ec), 0);
}

// ---------------- MFMA dual GEMM, M=16/wave, LDS-staged fp16 B, fp16 A ------
template <int KPAD>
__global__ __launch_bounds__(256, 4) void k_gemm2m(const __half* __restrict__ A,
                                                   const unsigned short* __restrict__ WfL,
                                                   const unsigned short* __restrict__ WfR,
                                                   const float* __restrict__ bl_,
                                                   const float* __restrict__ br_,
                                                   __half* __restrict__ outl,
                                                   __half* __restrict__ outr) {
  __shared__ unsigned short Bs[2][4096];  // L, R (8 KB each)
  const int tid = threadIdx.x;
  const int wv = tid >> 6, lane = tid & 63;
  const int tw = blockIdx.x * 4 + wv;
  const bool active = (tw < N_NODES / 16);  // tail waves stay for barriers
  const int ml = lane & 15, q = lane >> 4;
  const int m0 = active ? tw * 16 : 0;
  f32x4 accL[8], accR[8];
  #pragma unroll
  for (int t = 0; t < 8; t++) {
    accL[t] = (f32x4){0.f, 0.f, 0.f, 0.f};
    accR[t] = (f32x4){0.f, 0.f, 0.f, 0.f};
  }
  const _Float16* ar0 = (const _Float16*)A + (size_t)(m0 + ml) * KPAD + q * 8;
  constexpr int NC = KPAD / 32;
  for (int c = 0; c < NC; c++) {
    // stage chunk: 512 fp16 frags (16 B each) per W
    #pragma unroll
    for (int i0 = 0; i0 < 512; i0 += 256) {
      int i = i0 + tid;
      size_t g = ((size_t)c * 512 + i) * 8;
      *(uint4*)(&Bs[0][i * 8]) = *(const uint4*)(WfL + g);
      *(uint4*)(&Bs[1][i * 8]) = *(const uint4*)(WfR + g);
    }
    __syncthreads();
    f16x8 a = *(const f16x8*)(ar0 + c * 32);
    #pragma unroll
    for (int t = 0; t < 8; t++) {
      int idx = (t * 64 + lane) * 8;
      f16x8 bL = *(const f16x8*)(&Bs[0][idx]);
      f16x8 bR = *(const f16x8*)(&Bs[1][idx]);
      accL[t] = __builtin_amdgcn_mfma_f32_16x16x32_f16(a, bL, accL[t], 0, 0, 0);
      accR[t] = __builtin_amdgcn_mfma_f32_16x16x32_f16(a, bR, accR[t], 0, 0, 0);
    }
    __syncthreads();
  }
  if (!active) return;
  // epilogue: C/D layout col=lane&15, row=quad*4+reg
  #pragma unroll
  for (int t = 0; t < 8; t++) {
    int n = t * 16 + ml;
    float bL = bl_[n], bR = br_[n];
    #pragma unroll
    for (int r = 0; r < 4; r++) {
      int row = m0 + q * 4 + r;
      outl[(size_t)row * 128 + n] = __float2half(accL[t][r] + bL);
      outr[(size_t)row * 128 + n] = __float2half(accR[t][r] + bR);
    }
  }
}

// ---------------- GATv2 edge pass: 32 lanes/node, packed fp16 math ----------
// Native _Float16 ext-vectors (v_pk_* ops); T12 row 255 = 0 so invalid
// lock-step slots contribute el=0 with NO masking (meta=255, ec=0).
// Plain-sum softmax (logits O(0.3)). Never use unvalidated scode as address.
__global__ __launch_bounds__(256) void k_gat(const __half* __restrict__ xl,
                                             const __half* __restrict__ xr,
                                             const int* __restrict__ indptr,
                                             const int4* __restrict__ scode,
                                             const __half* __restrict__ tabs,
                                             const float* __restrict__ att,
                                             const float* __restrict__ bias,
                                             __half* __restrict__ hout) {
  int wid = (blockIdx.x * 256 + threadIdx.x) >> 6;
  int nw = (gridDim.x * 256) >> 6;
  int lane = threadIdx.x & 63;
  int half_ = lane >> 5;
  int c = (lane & 31) * 4;  // 4 channels per lane
  const __half* T12 = tabs;  // 256 x 128 fp16
  uint2 vu = *(const uint2*)(tabs + 256 * 128 + c);
  h2 v01 = *reinterpret_cast<h2*>(&vu.x);
  h2 v23 = *reinterpret_cast<h2*>(&vu.y);
  float4 af = *(const float4*)(att + c);
  h2 a01 = {(_Float16)af.x, (_Float16)af.y};
  h2 a23 = {(_Float16)af.z, (_Float16)af.w};
  float4 b4 = *(const float4*)(bias + c);
  const h2 z2 = {(_Float16)0.f, (_Float16)0.f};
  const h2 k2 = {(_Float16)0.2f, (_Float16)0.2f};
  wid = __builtin_amdgcn_readfirstlane(wid);
  for (int nb = wid * 2; nb < N_NODES; nb += nw * 2) {
    int n = nb + half_;
    int beg = indptr[n], end1 = indptr[n + 1] - 1;  // end1 = self-loop slot
    int last = (end1 > beg) ? end1 - 1 : beg;       // clamp (may be unwritten!)
    uint2 xru = *(const uint2*)(xr + (size_t)n * 128 + c);
    h2 xr01 = *reinterpret_cast<h2*>(&xru.x);
    h2 xr23 = *reinterpret_cast<h2*>(&xru.y);
    float denom = 0.f;
    float4 acc = make_float4(0.f, 0.f, 0.f, 0.f);
    h2 els01 = z2, els23 = z2;
    int my_it = (end1 - beg + 3) >> 2;
    int ot = __shfl_xor(my_it, 32, 64);
    int iters = my_it > ot ? my_it : ot;  // wave-uniform
    for (int it = 0; it < iters; it++) {
      int j = beg + it * 4;
      int4 sc4[4]; h2 xl01[4], xl23[4]; float tt[4];
      bool val[4];
      #pragma unroll
      for (int u = 0; u < 4; u++) {
        val[u] = (j + u < end1);  // uniform within half
        int jj = val[u] ? j + u : last;
        sc4[u] = scode[jj];
      }
      #pragma unroll
      for (int u = 0; u < 4; u++) {
        int s = val[u] ? sc4[u].x : n;  // NEVER use poison as an address
        uint2 lv = *(const uint2*)(xl + (size_t)s * 128 + c);
        xl01[u] = *reinterpret_cast<h2*>(&lv.x);
        xl23[u] = *reinterpret_cast<h2*>(&lv.y);
      }
      #pragma unroll
      for (int u = 0; u < 4; u++) {
        int meta = val[u] ? (sc4[u].y & 255) : 255;  // row 255 = zeros
        float ec = val[u] ? __int_as_float(sc4[u].z) : 0.f;
        uint2 tv = *(const uint2*)(T12 + (size_t)meta * 128 + c);
        h2 t01 = *reinterpret_cast<h2*>(&tv.x);
        h2 t23 = *reinterpret_cast<h2*>(&tv.y);
        _Float16 eh = (_Float16)ec;
        h2 eh2 = {eh, eh};
        h2 el01 = eh2 * v01 + t01;
        h2 el23 = eh2 * v23 + t23;
        h2 m01 = xl01[u] + xr01 + el01;
        h2 m23 = xl23[u] + xr23 + el23;
        h2 l01 = __builtin_elementwise_max(m01, z2) + k2 * __builtin_elementwise_min(m01, z2);
        h2 l23 = __builtin_elementwise_max(m23, z2) + k2 * __builtin_elementwise_min(m23, z2);
        h2 d = l01 * a01 + l23 * a23;
        tt[u] = (float)d[0] + (float)d[1];
        els01 += el01;   // el=0 for invalid slots — no mask
        els23 += el23;
      }
      // 8 independent half-wave reduction chains (4 per node), 5 steps
      #pragma unroll
      for (int off = 1; off < 32; off <<= 1) {
        tt[0] += __shfl_xor(tt[0], off, 64);
        tt[1] += __shfl_xor(tt[1], off, 64);
        tt[2] += __shfl_xor(tt[2], off, 64);
        tt[3] += __shfl_xor(tt[3], off, 64);
      }
      #pragma unroll
      for (int u = 0; u < 4; u++) {
        float ex = val[u] ? __expf(tt[u]) : 0.f;
        denom += ex;
        acc.x += ex * (float)xl01[u][0];
        acc.y += ex * (float)xl01[u][1];
        acc.z += ex * (float)xl23[u][0];
        acc.w += ex * (float)xl23[u][1];
      }
    }
    // self-loop (always present, processed last) — fp32 path
    int cntn = end1 - beg;
    float inv_cnt = 1.0f / (float)(cntn > 0 ? cntn : 1);
    uint2 xnu = *(const uint2*)(xl + (size_t)n * 128 + c);
    h2 xn01 = *reinterpret_cast<h2*>(&xnu.x);
    h2 xn23 = *reinterpret_cast<h2*>(&xnu.y);
    float m0 = (float)xn01[0] + (float)xr01[0] + (float)els01[0] * inv_cnt;
    float m1 = (float)xn01[1] + (float)xr01[1] + (float)els01[1] * inv_cnt;
    float m2 = (float)xn23[0] + (float)xr23[0] + (float)els23[0] * inv_cnt;
    float m3 = (float)xn23[1] + (float)xr23[1] + (float)els23[1] * inv_cnt;
    float l0 = m0 > 0.f ? m0 : 0.2f * m0;
    float l1 = m1 > 0.f ? m1 : 0.2f * m1;
    float l2 = m2 > 0.f ? m2 : 0.2f * m2;
    float l3 = m3 > 0.f ? m3 : 0.2f * m3;
    float ts = l0 * af.x + l1 * af.y + l2 * af.z + l3 * af.w;
    #pragma unroll
    for (int off = 1; off < 32; off <<= 1) ts += __shfl_xor(ts, off, 64);
    float ex = __expf(ts);
    denom += ex;
    acc.x += ex * (float)xn01[0];
    acc.y += ex * (float)xn01[1];
    acc.z += ex * (float)xn23[0];
    acc.w += ex * (float)xn23[1];
    float invd = 1.0f / denom;
    float o0 = acc.x * invd + b4.x;
    float o1 = acc.y * invd + b4.y;
    float o2 = acc.z * invd + b4.z;
    float o3 = acc.w * invd + b4.w;
    o0 = o0 > 0.f ? o0 : 0.f;
    o1 = o1 > 0.f ? o1 : 0.f;
    o2 = o2 > 0.f ? o2 : 0.f;
    o3 = o3 > 0.f ? o3 : 0.f;
    h2 p01 = {(_Float16)o0, (_Float16)o1};
    h2 p23 = {(_Float16)o2, (_Float16)o3};
    uint2 st = make_uint2(*reinterpret_cast<unsigned*>(&p01),
                          *reinterpret_cast<unsigned*>(&p23));
    *(uint2*)(hout + (size_t)n * 128 + c) = st;
  }
}

// ---------------- readout: global max pool over 20 contiguous nodes --------
__global__ void k_readout(const __half* __restrict__ h, float* __restrict__ out) {
  int wid = (blockIdx.x * blockDim.x + threadIdx.x) >> 6;
  int lane = threadIdx.x & 63;
  if (wid >= N_GRAPHS) return;
  int c = lane * 2;
  float m0 = -1e30f, m1 = -1e30f;
  for (int i = 0; i < NPG; i++) {
    unsigned v = *(const unsigned*)(h + ((size_t)(wid * NPG + i)) * 128 + c);
    h2 f = *reinterpret_cast<h2*>(&v);
    m0 = fmaxf(m0, (float)f[0]);
    m1 = fmaxf(m1, (float)f[1]);
  }
  float2 o; o.x = m0; o.y = m1;
  *(float2*)(out + (size_t)wid * 128 + c) = o;
}

extern "C" void kernel_launch(void* const* d_in, const int* in_sizes, int n_in,
                              void* d_out, int out_size, void* d_ws, size_t ws_size,
                              hipStream_t stream) {
  (void)in_sizes; (void)n_in; (void)out_size; (void)ws_size;
  const float* x        = (const float*)d_in[0];
  const int*   eindex   = (const int*)d_in[1];
  const float* eattr    = (const float*)d_in[2];
  const float* atom_emb = (const float*)d_in[4];
  const float* bond_emb = (const float*)d_in[5];
  const float* bool_emb = (const float*)d_in[6];
  const float* Wn   = (const float*)d_in[7];
  const float* bn   = (const float*)d_in[8];
  const float* We   = (const float*)d_in[9];
  const float* be   = (const float*)d_in[10];
  const float* Wl1  = (const float*)d_in[11];
  const float* bl1  = (const float*)d_in[12];
  const float* Wr1  = (const float*)d_in[13];
  const float* br1  = (const float*)d_in[14];
  const float* Wedge1 = (const float*)d_in[15];
  const float* att1 = (const float*)d_in[16];
  const float* bias1 = (const float*)d_in[17];
  const float* Wl2  = (const float*)d_in[18];
  const float* bl2  = (const float*)d_in[19];
  const float* Wr2  = (const float*)d_in[20];
  const float* br2  = (const float*)d_in[21];
  const float* Wedge2 = (const float*)d_in[22];
  const float* att2 = (const float*)d_in[23];
  const float* bias2 = (const float*)d_in[24];

  const int* srcA = eindex;
  const int* dstA = eindex + N_EDGES;

  char* p = (char*)d_ws;
  auto alloc = [&](size_t bytes) {
    char* r = p;
    p += (bytes + 255) & ~(size_t)255;
    return r;
  };
  __half* h0     = (__half*)alloc((size_t)N_NODES * 64 * 2);
  __half* h      = (__half*)alloc((size_t)N_NODES * 128 * 2);
  __half* xl     = (__half*)alloc((size_t)N_NODES * 128 * 2);
  __half* xrb    = (__half*)alloc((size_t)N_NODES * 128 * 2);
  int*    cnt    = (int*)alloc((size_t)N_NODES * 4);
  int*    indptr = (int*)alloc((size_t)(N_NODES + 1) * 4);
  int*    cursor = (int*)alloc((size_t)N_NODES * 4);
  int4*   scode  = (int4*)alloc((size_t)(N_EDGES + N_NODES) * 16);
  __half* tabs   = (__half*)alloc((size_t)2 * TAB_STRIDE * 2);
  unsigned short* wfrag = (unsigned short*)alloc((size_t)(2 * F1 + 2 * F2) * 2);
  int*    bsum   = (int*)alloc((size_t)SCAN_NB * 4);

  (void)hipMemsetAsync(cnt, 0, (size_t)N_NODES * 4, stream);

  // fused prologue: encode | hist | tabs | prep
  k_prologue<<<NB_ENC + NB_HIST + 1 + 24, 256, 0, stream>>>(
      x, atom_emb, bool_emb, Wn, bn, h0, dstA, cnt,
      Wedge1, Wedge2, bond_emb, We, be, tabs,
      Wl1, Wr1, Wl2, Wr2, wfrag);
  k_scan1<<<SCAN_NB, 256, 0, stream>>>(cnt, bsum);
  k_scan2<<<1, 256, 0, stream>>>(bsum);
  k_scan3<<<SCAN_NB, 256, 0, stream>>>(cnt, bsum, indptr, cursor);
  k_fill<<<(N_EDGES + 255) / 256, 256, 0, stream>>>(srcA, dstA, eattr, cursor, scode);

  const unsigned short* f_l1 = wfrag;
  const unsigned short* f_r1 = wfrag + F1;
  const unsigned short* f_l2 = wfrag + 2 * F1;
  const unsigned short* f_r2 = wfrag + 2 * F1 + F2;

  const int GB2 = (N_NODES / 16 + 3) / 4;  // 1563 blocks of 4 waves

  // layer 1 (K=52 zero-padded to 64)
  k_gemm2m<64><<<GB2, 256, 0, stream>>>(h0, f_l1, f_r1, bl1, br1, xl, xrb);
  k_gat<<<2048, 256, 0, stream>>>(xl, xrb, indptr, scode, tabs, att1, bias1, h);

  // layer 2 (K=128)
  k_gemm2m<128><<<GB2, 256, 0, stream>>>(h, f_l2, f_r2, bl2, br2, xl, xrb);
  k_gat<<<2048, 256, 0, stream>>>(xl, xrb, indptr, scode, tabs + TAB_STRIDE, att2, bias2, h);

  // layer 3 (shared weights with layer 2)
  k_gemm2m<128><<<GB2, 256, 0, stream>>>(h, f_l2, f_r2, bl2, br2, xl, xrb);
  k_gat<<<2048, 256, 0, stream>>>(xl, xrb, indptr, scode, tabs + TAB_STRIDE, att2, bias2, h);

  k_readout<<<(N_GRAPHS * 64 + 255) / 256, 256, 0, stream>>>(h, (float*)d_out);
}

// Round 17
// 351.201 us; speedup vs baseline: 1.5251x; 1.1076x over previous
//
#include <hip/hip_runtime.h>
#include <hip/hip_fp16.h>

#define N_NODES 100000
#define N_EDGES 400000
#define N_GRAPHS 5000
#define NPG 20
#define SCAN_NB 256
#define SCAN_CHUNK ((N_NODES + SCAN_NB - 1) / SCAN_NB)  // 391
#define TAB_STRIDE (256 * 128 + 128)  // halves: T12[256][128] + v[128]
#define F1 8192   // ushorts per K=64 frag array (1024 frags * 8, fp16)
#define F2 16384  // ushorts per K=128 frag array (2048 frags * 8, fp16)
#define NB_ENC ((N_NODES + 255) / 256)   // 391
#define NB_HIST ((N_EDGES + 255) / 256)  // 1563

typedef __attribute__((ext_vector_type(8))) _Float16 f16x8;
typedef __attribute__((ext_vector_type(2))) _Float16 h2;
typedef __attribute__((ext_vector_type(4))) float f32x4;

// ---------------- fused prologue: encode_nodes | hist | tabs | prep ---------
__global__ __launch_bounds__(256) void k_prologue(
    const float* __restrict__ x, const float* __restrict__ atom_emb,
    const float* __restrict__ bool_emb, const float* __restrict__ Wn,
    const float* __restrict__ bn, __half* __restrict__ h0,
    const int* __restrict__ dst, int* __restrict__ cnt,
    const float* __restrict__ Wedge1, const float* __restrict__ Wedge2,
    const float* __restrict__ bond_emb, const float* __restrict__ We,
    const float* __restrict__ be, __half* __restrict__ tabs,
    const float* __restrict__ Wl1, const float* __restrict__ Wr1,
    const float* __restrict__ Wl2, const float* __restrict__ Wr2,
    unsigned short* __restrict__ fr) {
  int b = blockIdx.x, tid = threadIdx.x;
  if (b < NB_ENC) {
    // ---- node encoder: h0[N,64] fp16 (cols 52..63 zero) ----
    int n = b * 256 + tid;
    if (n >= N_NODES) return;
    const float* xr = x + (size_t)n * 14;
    __half* h = h0 + (size_t)n * 64;
    int ai = (int)xr[0];
    #pragma unroll
    for (int j = 0; j < 16; j++) h[j] = __float2half(atom_emb[ai * 16 + j]);
    float xc[10];
    #pragma unroll
    for (int k = 0; k < 10; k++) xc[k] = xr[1 + k];
    #pragma unroll
    for (int c = 0; c < 30; c++) {
      float s = bn[c];
      #pragma unroll
      for (int k = 0; k < 10; k++) s += xc[k] * Wn[k * 30 + c];
      h[16 + c] = __float2half(s);
    }
    #pragma unroll
    for (int t = 0; t < 3; t++) {
      int bb = (int)xr[11 + t];
      h[46 + 2 * t]     = __float2half(bool_emb[2 * bb]);
      h[46 + 2 * t + 1] = __float2half(bool_emb[2 * bb + 1]);
    }
    #pragma unroll
    for (int j = 52; j < 64; j++) h[j] = __float2half(0.0f);
  } else if (b < NB_ENC + NB_HIST) {
    // ---- in-degree histogram ----
    int e = (b - NB_ENC) * 256 + tid;
    if (e >= N_EDGES) return;
    atomicAdd(cnt + dst[e], 1);
  } else if (b == NB_ENC + NB_HIST) {
    // ---- fused logit table (fp16): T12[combo*32+bi], v; rows 22..31 = 0 ----
    int s = tid >> 7, c = tid & 127;
    const float* W = s ? Wedge2 : Wedge1;
    __half* T12 = tabs + (size_t)s * TAB_STRIDE;
    __half* v   = T12 + 256 * 128;
    float w8 = W[8 * 128 + c], w9 = W[9 * 128 + c];
    v[c] = __float2half(We[0] * w8 + We[1] * w9);
    float cst = be[0] * w8 + be[1] * w9;
    float bond[22];
    for (int bb = 0; bb < 22; bb++) {
      float acc = 0.f;
      #pragma unroll
      for (int k = 0; k < 8; k++) acc += bond_emb[bb * 8 + k] * W[k * 128 + c];
      bond[bb] = acc;
    }
    for (int combo = 0; combo < 8; combo++) {
      float t2 = cst;
      #pragma unroll
      for (int tt = 0; tt < 3; tt++) {
        int bt = (combo >> tt) & 1;
        t2 += bool_emb[bt * 2 + 0] * W[(10 + 2 * tt + 0) * 128 + c];
        t2 += bool_emb[bt * 2 + 1] * W[(10 + 2 * tt + 1) * 128 + c];
      }
      for (int bb = 0; bb < 22; bb++)
        T12[(combo * 32 + bb) * 128 + c] = __float2half(bond[bb] + t2);
      for (int bb = 22; bb < 32; bb++)   // incl. row 255 = zero (invalid slots)
        T12[(combo * 32 + bb) * 128 + c] = __float2half(0.f);
    }
  } else {
    // ---- W -> MFMA B-fragment prep (fp16, 8 halves = 16 B per frag) ----
    int g = (b - (NB_ENC + NB_HIST + 1)) * 256 + tid;
    const float* W; int K; unsigned short* base; int fl;
    if (g < 1024)      { W = Wl1; K = 52;  base = fr;               fl = g; }
    else if (g < 2048) { W = Wr1; K = 52;  base = fr + F1;          fl = g - 1024; }
    else if (g < 4096) { W = Wl2; K = 128; base = fr + 2 * F1;      fl = g - 2048; }
    else if (g < 6144) { W = Wr2; K = 128; base = fr + 2 * F1 + F2; fl = g - 4096; }
    else return;
    int l = fl & 63, ctn = fl >> 6;
    int tn = ctn & 7, c = ctn >> 3;
    int n = tn * 16 + (l & 15);
    int kb = c * 32 + (l >> 4) * 8;
    unsigned h8[8];
    #pragma unroll
    for (int j = 0; j < 8; j++) {
      int k = kb + j;
      float v = (k < K) ? W[(size_t)k * 128 + n] : 0.f;
      __half hv = __float2half(v);
      h8[j] = (unsigned)*(unsigned short*)&hv;
    }
    uint4 hv4 = make_uint4(h8[0] | (h8[1] << 16), h8[2] | (h8[3] << 16),
                           h8[4] | (h8[5] << 16), h8[6] | (h8[7] << 16));
    *(uint4*)(base + (size_t)fl * 8) = hv4;
  }
}

// ---------------- hierarchical scan over (cnt[n]+1), 3 phases ---------------
__global__ __launch_bounds__(256) void k_scan1(const int* __restrict__ cnt,
                                               int* __restrict__ bsum) {
  __shared__ int red[256];
  int b = blockIdx.x, t = threadIdx.x;
  int beg = b * SCAN_CHUNK;
  int end = beg + SCAN_CHUNK; if (end > N_NODES) end = N_NODES;
  int s = 0;
  for (int i = beg + t; i < end; i += 256) s += cnt[i] + 1;
  red[t] = s;
  __syncthreads();
  for (int off = 128; off > 0; off >>= 1) {
    if (t < off) red[t] += red[t + off];
    __syncthreads();
  }
  if (t == 0) bsum[b] = red[0];
}

__global__ __launch_bounds__(256) void k_scan2(int* __restrict__ bsum) {
  __shared__ int sh[256];
  int t = threadIdx.x;
  sh[t] = bsum[t];
  __syncthreads();
  for (int off = 1; off < 256; off <<= 1) {
    int v = (t >= off) ? sh[t - off] : 0;
    __syncthreads();
    sh[t] += v;
    __syncthreads();
  }
  bsum[t] = (t > 0) ? sh[t - 1] : 0;  // exclusive
}

__global__ __launch_bounds__(256) void k_scan3(const int* __restrict__ cnt,
                                               const int* __restrict__ bsum,
                                               int* __restrict__ indptr,
                                               int* __restrict__ cursor) {
  __shared__ int sh[256];
  __shared__ int carry;
  int b = blockIdx.x, t = threadIdx.x;
  int beg = b * SCAN_CHUNK;
  int end = beg + SCAN_CHUNK; if (end > N_NODES) end = N_NODES;
  if (t == 0) carry = bsum[b];
  __syncthreads();
  for (int base = beg; base < end; base += 256) {
    int i = base + t;
    int v = (i < end) ? cnt[i] + 1 : 0;
    sh[t] = v;
    __syncthreads();
    for (int off = 1; off < 256; off <<= 1) {
      int u = (t >= off) ? sh[t - off] : 0;
      __syncthreads();
      sh[t] += u;
      __syncthreads();
    }
    int excl = sh[t] - v;
    if (i < end) {
      int val = carry + excl;
      indptr[i] = val;
      cursor[i] = val;
    }
    __syncthreads();
    if (t == 255) carry += sh[255];
    __syncthreads();
  }
  if (b == 0 && t == 0) indptr[N_NODES] = N_EDGES + N_NODES;
}

// ---------------- CSR fill: ordinary edges into slots [beg, end-1) ----------
__global__ void k_fill(const int* __restrict__ srcA,
                       const int* __restrict__ dst,
                       const float* __restrict__ eattr,
                       int* __restrict__ cursor,
                       int4* __restrict__ scode) {
  int e = blockIdx.x * blockDim.x + threadIdx.x;
  if (e >= N_EDGES) return;
  const float* r = eattr + (size_t)e * 5;
  int bi = (int)r[0];
  float ec = r[1];
  int combo = (int)r[2] + 2 * (int)r[3] + 4 * (int)r[4];
  int meta = bi | (combo << 5);
  int d = dst[e];
  int p = atomicAdd(&cursor[d], 1);
  scode[p] = make_int4(srcA[e], meta, __float_as_int(ec), 0);
}

// ---------------- MFMA dual GEMM, M=16/wave, LDS-staged fp16 B, fp16 A ------
template <int KPAD>
__global__ __launch_bounds__(256, 4) void k_gemm2m(const __half* __restrict__ A,
                                                   const unsigned short* __restrict__ WfL,
                                                   const unsigned short* __restrict__ WfR,
                                                   const float* __restrict__ bl_,
                                                   const float* __restrict__ br_,
                                                   __half* __restrict__ outl,
                                                   __half* __restrict__ outr) {
  __shared__ unsigned short Bs[2][4096];  // L, R (8 KB each)
  const int tid = threadIdx.x;
  const int wv = tid >> 6, lane = tid & 63;
  const int tw = blockIdx.x * 4 + wv;
  const bool active = (tw < N_NODES / 16);  // tail waves stay for barriers
  const int ml = lane & 15, q = lane >> 4;
  const int m0 = active ? tw * 16 : 0;
  f32x4 accL[8], accR[8];
  #pragma unroll
  for (int t = 0; t < 8; t++) {
    accL[t] = (f32x4){0.f, 0.f, 0.f, 0.f};
    accR[t] = (f32x4){0.f, 0.f, 0.f, 0.f};
  }
  const _Float16* ar0 = (const _Float16*)A + (size_t)(m0 + ml) * KPAD + q * 8;
  constexpr int NC = KPAD / 32;
  for (int c = 0; c < NC; c++) {
    // stage chunk: 512 fp16 frags (16 B each) per W
    #pragma unroll
    for (int i0 = 0; i0 < 512; i0 += 256) {
      int i = i0 + tid;
      size_t g = ((size_t)c * 512 + i) * 8;
      *(uint4*)(&Bs[0][i * 8]) = *(const uint4*)(WfL + g);
      *(uint4*)(&Bs[1][i * 8]) = *(const uint4*)(WfR + g);
    }
    __syncthreads();
    f16x8 a = *(const f16x8*)(ar0 + c * 32);
    #pragma unroll
    for (int t = 0; t < 8; t++) {
      int idx = (t * 64 + lane) * 8;
      f16x8 bL = *(const f16x8*)(&Bs[0][idx]);
      f16x8 bR = *(const f16x8*)(&Bs[1][idx]);
      accL[t] = __builtin_amdgcn_mfma_f32_16x16x32_f16(a, bL, accL[t], 0, 0, 0);
      accR[t] = __builtin_amdgcn_mfma_f32_16x16x32_f16(a, bR, accR[t], 0, 0, 0);
    }
    __syncthreads();
  }
  if (!active) return;
  // epilogue: C/D layout col=lane&15, row=quad*4+reg
  #pragma unroll
  for (int t = 0; t < 8; t++) {
    int n = t * 16 + ml;
    float bL = bl_[n], bR = br_[n];
    #pragma unroll
    for (int r = 0; r < 4; r++) {
      int row = m0 + q * 4 + r;
      outl[(size_t)row * 128 + n] = __float2half(accL[t][r] + bL);
      outr[(size_t)row * 128 + n] = __float2half(accR[t][r] + bR);
    }
  }
}

// ---------------- GATv2 edge pass: 16 lanes/node (4 nodes/wave) -------------
// 8 ch/lane => 16 B/lane gathers (dwordx4, 4 rows per instruction);
// 4-step quarter-wave reductions. T12 row 255 = 0 so invalid lock-step slots
// contribute el=0 with no masking. Plain-sum softmax (logits O(0.3)).
// Never use unvalidated scode data as an address.
__global__ __launch_bounds__(256) void k_gat(const __half* __restrict__ xl,
                                             const __half* __restrict__ xr,
                                             const int* __restrict__ indptr,
                                             const int4* __restrict__ scode,
                                             const __half* __restrict__ tabs,
                                             const float* __restrict__ att,
                                             const float* __restrict__ bias,
                                             __half* __restrict__ hout) {
  int wid = (blockIdx.x * 256 + threadIdx.x) >> 6;
  int nw = (gridDim.x * 256) >> 6;
  int lane = threadIdx.x & 63;
  int q4 = lane >> 4;            // quarter (node within wave)
  int c = (lane & 15) * 8;       // 8 channels per lane
  const __half* T12 = tabs;      // 256 x 128 fp16
  uint4 vu = *(const uint4*)(tabs + 256 * 128 + c);
  h2 v4[4] = {*reinterpret_cast<h2*>(&vu.x), *reinterpret_cast<h2*>(&vu.y),
              *reinterpret_cast<h2*>(&vu.z), *reinterpret_cast<h2*>(&vu.w)};
  float4 af0 = *(const float4*)(att + c);
  float4 af1 = *(const float4*)(att + c + 4);
  h2 a4[4] = {{(_Float16)af0.x, (_Float16)af0.y}, {(_Float16)af0.z, (_Float16)af0.w},
              {(_Float16)af1.x, (_Float16)af1.y}, {(_Float16)af1.z, (_Float16)af1.w}};
  float bb[8];
  {
    float4 b0 = *(const float4*)(bias + c);
    float4 b1 = *(const float4*)(bias + c + 4);
    bb[0] = b0.x; bb[1] = b0.y; bb[2] = b0.z; bb[3] = b0.w;
    bb[4] = b1.x; bb[5] = b1.y; bb[6] = b1.z; bb[7] = b1.w;
  }
  const h2 z2 = {(_Float16)0.f, (_Float16)0.f};
  const h2 k2 = {(_Float16)0.2f, (_Float16)0.2f};
  wid = __builtin_amdgcn_readfirstlane(wid);
  for (int nb = wid * 4; nb < N_NODES; nb += nw * 4) {
    int n = nb + q4;  // N_NODES % 4 == 0 -> always valid
    int beg = indptr[n], end1 = indptr[n + 1] - 1;  // end1 = self-loop slot
    int last = (end1 > beg) ? end1 - 1 : beg;       // clamp (may be unwritten!)
    uint4 xru = *(const uint4*)(xr + (size_t)n * 128 + c);
    h2 xrv[4] = {*reinterpret_cast<h2*>(&xru.x), *reinterpret_cast<h2*>(&xru.y),
                 *reinterpret_cast<h2*>(&xru.z), *reinterpret_cast<h2*>(&xru.w)};
    float denom = 0.f;
    float acc[8] = {0.f, 0.f, 0.f, 0.f, 0.f, 0.f, 0.f, 0.f};
    h2 els[4] = {z2, z2, z2, z2};
    int my_it = (end1 - beg + 3) >> 2;
    int m1 = my_it, m2;
    m2 = __shfl_xor(m1, 16, 64); m1 = m1 > m2 ? m1 : m2;
    m2 = __shfl_xor(m1, 32, 64); m1 = m1 > m2 ? m1 : m2;
    int iters = m1;  // wave-uniform
    for (int it = 0; it < iters; it++) {
      int j = beg + it * 4;
      int4 sc4[4]; h2 xlv[4][4]; float tt[4];
      bool val[4];
      #pragma unroll
      for (int u = 0; u < 4; u++) {
        val[u] = (j + u < end1);  // uniform within quarter
        int jj = val[u] ? j + u : last;
        sc4[u] = scode[jj];
      }
      #pragma unroll
      for (int u = 0; u < 4; u++) {
        int s = val[u] ? sc4[u].x : n;  // NEVER use poison as an address
        uint4 lv = *(const uint4*)(xl + (size_t)s * 128 + c);
        xlv[u][0] = *reinterpret_cast<h2*>(&lv.x);
        xlv[u][1] = *reinterpret_cast<h2*>(&lv.y);
        xlv[u][2] = *reinterpret_cast<h2*>(&lv.z);
        xlv[u][3] = *reinterpret_cast<h2*>(&lv.w);
      }
      #pragma unroll
      for (int u = 0; u < 4; u++) {
        int meta = val[u] ? (sc4[u].y & 255) : 255;  // row 255 = zeros
        float ec = val[u] ? __int_as_float(sc4[u].z) : 0.f;
        uint4 tv = *(const uint4*)(T12 + (size_t)meta * 128 + c);
        h2 t4[4] = {*reinterpret_cast<h2*>(&tv.x), *reinterpret_cast<h2*>(&tv.y),
                    *reinterpret_cast<h2*>(&tv.z), *reinterpret_cast<h2*>(&tv.w)};
        _Float16 eh = (_Float16)ec;
        h2 eh2 = {eh, eh};
        h2 d = z2;
        #pragma unroll
        for (int k = 0; k < 4; k++) {
          h2 el = eh2 * v4[k] + t4[k];
          h2 m = xlv[u][k] + xrv[k] + el;
          h2 l = __builtin_elementwise_max(m, z2) + k2 * __builtin_elementwise_min(m, z2);
          d += l * a4[k];
          els[k] += el;  // el=0 for invalid slots — no mask
        }
        tt[u] = (float)d[0] + (float)d[1];
      }
      // 4 independent quarter-wave reduction chains, 4 steps
      #pragma unroll
      for (int off = 1; off < 16; off <<= 1) {
        tt[0] += __shfl_xor(tt[0], off, 64);
        tt[1] += __shfl_xor(tt[1], off, 64);
        tt[2] += __shfl_xor(tt[2], off, 64);
        tt[3] += __shfl_xor(tt[3], off, 64);
      }
      #pragma unroll
      for (int u = 0; u < 4; u++) {
        float ex = val[u] ? __expf(tt[u]) : 0.f;
        denom += ex;
        #pragma unroll
        for (int k = 0; k < 4; k++) {
          acc[2 * k]     += ex * (float)xlv[u][k][0];
          acc[2 * k + 1] += ex * (float)xlv[u][k][1];
        }
      }
    }
    // self-loop (always present, processed last) — fp32 path
    int cntn = end1 - beg;
    float inv_cnt = 1.0f / (float)(cntn > 0 ? cntn : 1);
    uint4 xnu = *(const uint4*)(xl + (size_t)n * 128 + c);
    h2 xn[4] = {*reinterpret_cast<h2*>(&xnu.x), *reinterpret_cast<h2*>(&xnu.y),
                *reinterpret_cast<h2*>(&xnu.z), *reinterpret_cast<h2*>(&xnu.w)};
    float afv[8] = {af0.x, af0.y, af0.z, af0.w, af1.x, af1.y, af1.z, af1.w};
    float ts = 0.f;
    float xnf[8];
    #pragma unroll
    for (int k = 0; k < 4; k++) {
      #pragma unroll
      for (int hh = 0; hh < 2; hh++) {
        int i = 2 * k + hh;
        xnf[i] = (float)xn[k][hh];
        float m = xnf[i] + (float)xrv[k][hh] + (float)els[k][hh] * inv_cnt;
        float l = m > 0.f ? m : 0.2f * m;
        ts += l * afv[i];
      }
    }
    #pragma unroll
    for (int off = 1; off < 16; off <<= 1) ts += __shfl_xor(ts, off, 64);
    float ex = __expf(ts);
    denom += ex;
    #pragma unroll
    for (int i = 0; i < 8; i++) acc[i] += ex * xnf[i];
    float invd = 1.0f / denom;
    h2 p[4];
    #pragma unroll
    for (int k = 0; k < 4; k++) {
      float o0 = acc[2 * k] * invd + bb[2 * k];
      float o1 = acc[2 * k + 1] * invd + bb[2 * k + 1];
      o0 = o0 > 0.f ? o0 : 0.f;
      o1 = o1 > 0.f ? o1 : 0.f;
      p[k] = (h2){(_Float16)o0, (_Float16)o1};
    }
    uint4 st = make_uint4(*reinterpret_cast<unsigned*>(&p[0]),
                          *reinterpret_cast<unsigned*>(&p[1]),
                          *reinterpret_cast<unsigned*>(&p[2]),
                          *reinterpret_cast<unsigned*>(&p[3]));
    *(uint4*)(hout + (size_t)n * 128 + c) = st;
  }
}

// ---------------- readout: global max pool over 20 contiguous nodes --------
__global__ void k_readout(const __half* __restrict__ h, float* __restrict__ out) {
  int wid = (blockIdx.x * blockDim.x + threadIdx.x) >> 6;
  int lane = threadIdx.x & 63;
  if (wid >= N_GRAPHS) return;
  int c = lane * 2;
  float m0 = -1e30f, m1 = -1e30f;
  for (int i = 0; i < NPG; i++) {
    unsigned v = *(const unsigned*)(h + ((size_t)(wid * NPG + i)) * 128 + c);
    h2 f = *reinterpret_cast<h2*>(&v);
    m0 = fmaxf(m0, (float)f[0]);
    m1 = fmaxf(m1, (float)f[1]);
  }
  float2 o; o.x = m0; o.y = m1;
  *(float2*)(out + (size_t)wid * 128 + c) = o;
}

extern "C" void kernel_launch(void* const* d_in, const int* in_sizes, int n_in,
                              void* d_out, int out_size, void* d_ws, size_t ws_size,
                              hipStream_t stream) {
  (void)in_sizes; (void)n_in; (void)out_size; (void)ws_size;
  const float* x        = (const float*)d_in[0];
  const int*   eindex   = (const int*)d_in[1];
  const float* eattr    = (const float*)d_in[2];
  const float* atom_emb = (const float*)d_in[4];
  const float* bond_emb = (const float*)d_in[5];
  const float* bool_emb = (const float*)d_in[6];
  const float* Wn   = (const float*)d_in[7];
  const float* bn   = (const float*)d_in[8];
  const float* We   = (const float*)d_in[9];
  const float* be   = (const float*)d_in[10];
  const float* Wl1  = (const float*)d_in[11];
  const float* bl1  = (const float*)d_in[12];
  const float* Wr1  = (const float*)d_in[13];
  const float* br1  = (const float*)d_in[14];
  const float* Wedge1 = (const float*)d_in[15];
  const float* att1 = (const float*)d_in[16];
  const float* bias1 = (const float*)d_in[17];
  const float* Wl2  = (const float*)d_in[18];
  const float* bl2  = (const float*)d_in[19];
  const float* Wr2  = (const float*)d_in[20];
  const float* br2  = (const float*)d_in[21];
  const float* Wedge2 = (const float*)d_in[22];
  const float* att2 = (const float*)d_in[23];
  const float* bias2 = (const float*)d_in[24];

  const int* srcA = eindex;
  const int* dstA = eindex + N_EDGES;

  char* p = (char*)d_ws;
  auto alloc = [&](size_t bytes) {
    char* r = p;
    p += (bytes + 255) & ~(size_t)255;
    return r;
  };
  __half* h0     = (__half*)alloc((size_t)N_NODES * 64 * 2);
  __half* h      = (__half*)alloc((size_t)N_NODES * 128 * 2);
  __half* xl     = (__half*)alloc((size_t)N_NODES * 128 * 2);
  __half* xrb    = (__half*)alloc((size_t)N_NODES * 128 * 2);
  int*    cnt    = (int*)alloc((size_t)N_NODES * 4);
  int*    indptr = (int*)alloc((size_t)(N_NODES + 1) * 4);
  int*    cursor = (int*)alloc((size_t)N_NODES * 4);
  int4*   scode  = (int4*)alloc((size_t)(N_EDGES + N_NODES) * 16);
  __half* tabs   = (__half*)alloc((size_t)2 * TAB_STRIDE * 2);
  unsigned short* wfrag = (unsigned short*)alloc((size_t)(2 * F1 + 2 * F2) * 2);
  int*    bsum   = (int*)alloc((size_t)SCAN_NB * 4);

  (void)hipMemsetAsync(cnt, 0, (size_t)N_NODES * 4, stream);

  // fused prologue: encode | hist | tabs | prep
  k_prologue<<<NB_ENC + NB_HIST + 1 + 24, 256, 0, stream>>>(
      x, atom_emb, bool_emb, Wn, bn, h0, dstA, cnt,
      Wedge1, Wedge2, bond_emb, We, be, tabs,
      Wl1, Wr1, Wl2, Wr2, wfrag);
  k_scan1<<<SCAN_NB, 256, 0, stream>>>(cnt, bsum);
  k_scan2<<<1, 256, 0, stream>>>(bsum);
  k_scan3<<<SCAN_NB, 256, 0, stream>>>(cnt, bsum, indptr, cursor);
  k_fill<<<(N_EDGES + 255) / 256, 256, 0, stream>>>(srcA, dstA, eattr, cursor, scode);

  const unsigned short* f_l1 = wfrag;
  const unsigned short* f_r1 = wfrag + F1;
  const unsigned short* f_l2 = wfrag + 2 * F1;
  const unsigned short* f_r2 = wfrag + 2 * F1 + F2;

  const int GB2 = (N_NODES / 16 + 3) / 4;  // 1563 blocks of 4 waves

  // layer 1 (K=52 zero-padded to 64)
  k_gemm2m<64><<<GB2, 256, 0, stream>>>(h0, f_l1, f_r1, bl1, br1, xl, xrb);
  k_gat<<<2048, 256, 0, stream>>>(xl, xrb, indptr, scode, tabs, att1, bias1, h);

  // layer 2 (K=128)
  k_gemm2m<128><<<GB2, 256, 0, stream>>>(h, f_l2, f_r2, bl2, br2, xl, xrb);
  k_gat<<<2048, 256, 0, stream>>>(xl, xrb, indptr, scode, tabs + TAB_STRIDE, att2, bias2, h);

  // layer 3 (shared weights with layer 2)
  k_gemm2m<128><<<GB2, 256, 0, stream>>>(h, f_l2, f_r2, bl2, br2, xl, xrb);
  k_gat<<<2048, 256, 0, stream>>>(xl, xrb, indptr, scode, tabs + TAB_STRIDE, att2, bias2, h);

  k_readout<<<(N_GRAPHS * 64 + 255) / 256, 256, 0, stream>>>(h, (float*)d_out);
}